// Round 10
// baseline (396.865 us; speedup 1.0000x reference)
//
#include <hip/hip_runtime.h>
#include <hip/hip_fp16.h>
#include <math.h>

#define WAVE   64
#define NPB    32          // nodes per window (power of 2, aligned -> key = ei&31)
#define BLOCKT 256
#define SMAX   2           // stashed 1024-edge chunks (covers <=2048 edges/window)

// ---- constants from the reference ----
#define KC        2.2281692032865347f   // 7/pi
#define H         0.05f
#define INV_H2    400.0f
#define INV_H3    8000.0f
#define EPS_REF   0.00025f              // h^2 * 0.1
#define K_OUT     0.24261080f           // 2*h*DELTA*C0
#define REST_RHO  1000.0f

__device__ __forceinline__ float wendland_dkdq(float q) {
    float o = 1.f - q;
    return -20.f * q * o * o * o * KC;
}

union H2F { __half2 h; float f; };
__device__ __forceinline__ float   h2_as_f(__half2 h) { H2F u; u.h = h; return u.f; }
__device__ __forceinline__ __half2 f_as_h2(float f)   { H2F u; u.f = f; return u.h; }

// ---------------------------------------------------------------------------
// 4-edge-per-lane segmented reduction via shuffle scan (R0-proven).
// Equal keys contiguous in lane order; key<0 skipped. base may be LDS.
// Scan capped at d<=16 (reach 31 lanes; runs up to ~124 edges OK; degrees
// ~Poisson(32), max ~60 -> 2x margin). Correctness-proven R1/R3/R4/R8.
// ---------------------------------------------------------------------------
template<int NV>
__device__ __forceinline__ void seg_reduce4(const int k[4], float v[4][NV], float* base) {
    const int lane = threadIdx.x & (WAVE - 1);
    const int k0 = k[0], k3 = k[3];
    const bool split = (k0 != k3);
    const int firstLen  = (k[1]==k0) ? ((k[2]==k0) ? ((k[3]==k0)?4:3) : 2) : 1;
    const int lastStart = (k[2]==k3) ? ((k[1]==k3) ? ((k[0]==k3)?0:1) : 2) : 3;

    float vin[NV], vfirst[NV];
#pragma unroll
    for (int c = 0; c < NV; ++c) {
        float s = v[3][c];
        if (lastStart <= 2) s += v[2][c];
        if (lastStart <= 1) s += v[1][c];
        if (lastStart == 0) s += v[0][c];
        vin[c] = s;
        float f = v[0][c];
        if (firstLen >= 2) f += v[1][c];
        if (firstLen >= 3) f += v[2][c];
        if (firstLen >= 4) f += v[3][c];
        vfirst[c] = f;
    }
#pragma unroll
    for (int idx = 1; idx <= 2; ++idx) {
        if (idx >= firstLen && idx < lastStart && k[idx] >= 0) {
#pragma unroll
            for (int c = 0; c < NV; ++c)
                atomicAdd(base + (size_t)k[idx] * NV + c, v[idx][c]);
        }
    }
    float S[NV];
#pragma unroll
    for (int c = 0; c < NV; ++c) S[c] = vin[c];
    const int klast = k3;
#pragma unroll
    for (int d = 1; d <= 16; d <<= 1) {   // 5 steps (bound above)
        int okey = __shfl_up(klast, d, WAVE);
        float ov[NV];
#pragma unroll
        for (int c = 0; c < NV; ++c) ov[c] = __shfl_up(S[c], d, WAVE);
        if (lane >= d && okey == klast) {
#pragma unroll
            for (int c = 0; c < NV; ++c) S[c] += ov[c];
        }
    }
    const int prevk = __shfl_up(klast, 1, WAVE);
    float P[NV];
#pragma unroll
    for (int c = 0; c < NV; ++c) P[c] = __shfl_up(S[c], 1, WAVE);
    if (split && k0 >= 0) {
        const bool carry = (lane > 0 && prevk == k0);
#pragma unroll
        for (int c = 0; c < NV; ++c)
            atomicAdd(base + (size_t)k0 * NV + c, vfirst[c] + (carry ? P[c] : 0.f));
    }
    const int nk0 = __shfl_down(k0, 1, WAVE);
    const bool tail = (lane == WAVE - 1) || (nk0 != klast);
    if (tail && klast >= 0) {
#pragma unroll
        for (int c = 0; c < NV; ++c)
            atomicAdd(base + (size_t)klast * NV + c, S[c]);
    }
}

struct EW { int jv[4]; float qv[4], dxv[4], dyv[4]; int kv[4]; bool okv[4]; };

// loads 4 edges + their precomputed 8-bit window keys
__device__ __forceinline__ void load_win(long e0, int beg, int end, int E,
        const int* __restrict__ ej, const float* __restrict__ qarr,
        const float2* __restrict__ dirs, const unsigned char* __restrict__ key8,
        EW& w) {
    if (e0 + 3 < (long)E) {
        int4   j4 = *(const int4*)(ej + e0);
        float4 q4 = *(const float4*)(qarr + e0);
        float4 dA = *(const float4*)((const float*)dirs + 2 * e0);
        float4 dB = *(const float4*)((const float*)dirs + 2 * e0 + 4);
        uchar4 kk = *(const uchar4*)(key8 + e0);
        w.jv[0]=j4.x; w.jv[1]=j4.y; w.jv[2]=j4.z; w.jv[3]=j4.w;
        w.qv[0]=q4.x; w.qv[1]=q4.y; w.qv[2]=q4.z; w.qv[3]=q4.w;
        w.dxv[0]=dA.x; w.dyv[0]=dA.y; w.dxv[1]=dA.z; w.dyv[1]=dA.w;
        w.dxv[2]=dB.x; w.dyv[2]=dB.y; w.dxv[3]=dB.z; w.dyv[3]=dB.w;
        w.kv[0]=kk.x; w.kv[1]=kk.y; w.kv[2]=kk.z; w.kv[3]=kk.w;
    } else {
#pragma unroll
        for (int u = 0; u < 4; ++u) {
            long e = e0 + u;
            if (e < (long)E) {
                w.jv[u] = ej[e]; w.qv[u] = qarr[e]; w.kv[u] = key8[e];
                float2 d = dirs[e]; w.dxv[u] = d.x; w.dyv[u] = d.y;
            } else { w.jv[u]=0; w.qv[u]=0.f; w.dxv[u]=0.f; w.dyv[u]=0.f; w.kv[u]=0; }
        }
    }
#pragma unroll
    for (int u = 0; u < 4; ++u) {
        long e = e0 + u;
        w.okv[u] = (e >= (long)beg) && (e < (long)end);
    }
}

// rowptr[t]=first edge with i>=t; vd=(vol,dens); key8[e]=ei[e]&31 (window-local)
__global__ void k_prep(const int* __restrict__ ei, const float* __restrict__ vol,
                       const float* __restrict__ dens, int* __restrict__ rowptr,
                       float2* __restrict__ vd, unsigned char* __restrict__ key8,
                       int N, int E) {
    int e = blockIdx.x * blockDim.x + threadIdx.x;
    if (e <= E) {
        int prev = (e == 0) ? -1 : ei[e - 1];
        int cur  = (e == E) ? N  : ei[e];
        for (int t = prev + 1; t <= cur; ++t) rowptr[t] = e;
        if (e < E) key8[e] = (unsigned char)(cur & (NPB - 1));
    }
    if (e < N) vd[e] = make_float2(vol[e], dens[e]);
}

// Fused A+B+C+term1/2 of D (R8-proven body; only launch_bounds changed 4->8:
// VGPR=56 fits the 64-reg cap at 8 waves/EU, so residency doubles, no spill).
__global__ __launch_bounds__(BLOCKT, 8)
void k_AC(const int* __restrict__ ej, const float* __restrict__ qarr,
          const float2* __restrict__ dirs, const float2* __restrict__ vd,
          const int* __restrict__ rowptr, const unsigned char* __restrict__ key8,
          __half2* __restrict__ cst,
          float2* __restrict__ g2, float* __restrict__ outp, int N, int E) {
    __shared__ float  acc6[NPB * 6];     // m00,m01,m11,A,Bx,By
    __shared__ float  Lild[NPB * 3];
    __shared__ float  gld[NPB * 2];
    __shared__ float2 vdl[NPB];
    const int tid = threadIdx.x;
    const int n0  = blockIdx.x * NPB;
    const int nHi = min(n0 + NPB, N);
    if (tid < NPB && n0 + tid < N) vdl[tid] = vd[n0 + tid];
    if (tid < NPB * 6) acc6[tid] = 0.f;
    if (tid < NPB * 2) gld[tid] = 0.f;
    __syncthreads();
    const int  beg = rowptr[n0], end = rowptr[nHi];   // uniform -> scalar loads
    const long beg4 = (long)beg & ~3L;
    const int  waveBase = tid & ~(WAVE - 1);

    int   li_s[4 * SMAX];
    float gwx_s[4 * SMAX], gwy_s[4 * SMAX], val_s[4 * SMAX];
#pragma unroll
    for (int x = 0; x < 4 * SMAX; ++x) { li_s[x] = -1; gwx_s[x]=gwy_s[x]=val_s[x]=0.f; }

    // ---- phase A ----
#pragma unroll
    for (int c = 0; c < SMAX; ++c) {
        long ebw = beg4 + ((long)c * BLOCKT + waveBase) * 4;
        if (ebw < (long)end) {
            long e0 = beg4 + ((long)c * BLOCKT + tid) * 4;
            EW wd; load_win(e0, beg, end, E, ej, qarr, dirs, key8, wd);
            const bool all4 = wd.okv[0] && wd.okv[1] && wd.okv[2] && wd.okv[3];
            float4 cpack;
            int k[4]; float v[4][6];
#pragma unroll
            for (int u = 0; u < 4; ++u) {
                k[u] = -1;
#pragma unroll
                for (int c2 = 0; c2 < 6; ++c2) v[u][c2] = 0.f;
                if (wd.okv[u]) {
                    int li = wd.kv[u];                 // direct key, no search
                    float q = wd.qv[u], dx = wd.dxv[u], dy = wd.dyv[u];
                    float2 vdj = vd[wd.jv[u]];
                    float wq = wendland_dkdq(q);
                    float t  = q * wq * INV_H2;        // unit dirs: gw.r_ba = -t
                    float s  = -2.f * vdj.x * t;       // >= 0
                    float w2 = wq * INV_H3;
                    float gwx = dx * w2, gwy = dy * w2;
                    float rx = -dx * q * H, ry = -dy * q * H;
                    float rji2 = rx * rx + ry * ry + EPS_REF;
                    float gT = -t / rji2;
                    float gv = gT * vdj.x;
                    float rho_ba = REST_RHO * (vdj.y - vdl[li].y);
                    k[u] = li;
                    v[u][0] = s * dx * dx; v[u][1] = s * dx * dy; v[u][2] = s * dy * dy;
                    v[u][3] = rho_ba * gv; v[u][4] = rx * gv;    v[u][5] = ry * gv;
                    __half2 cp = __floats2half2_rn(0.5f * rx * gv, 0.5f * ry * gv);
                    if (all4) (&cpack.x)[u] = h2_as_f(cp);
                    else      cst[e0 + u] = cp;
                    li_s[c*4+u] = li; gwx_s[c*4+u] = gwx; gwy_s[c*4+u] = gwy;
                    val_s[c*4+u] = 2.f * rho_ba * vdj.x;
                }
            }
            if (all4) ((float4*)cst)[e0 >> 2] = cpack;
            seg_reduce4<6>(k, v, acc6);
        }
    }
    // overflow (window > SMAX*1024 edges; practically never at avg degree 32)
    for (int c = SMAX; ; ++c) {
        long ebw = beg4 + ((long)c * BLOCKT + waveBase) * 4;
        if (ebw >= (long)end) break;
        long e0 = beg4 + ((long)c * BLOCKT + tid) * 4;
        EW wd; load_win(e0, beg, end, E, ej, qarr, dirs, key8, wd);
        int k[4]; float v[4][6];
#pragma unroll
        for (int u = 0; u < 4; ++u) {
            k[u] = -1;
#pragma unroll
            for (int c2 = 0; c2 < 6; ++c2) v[u][c2] = 0.f;
            if (wd.okv[u]) {
                int li = wd.kv[u];
                float q = wd.qv[u], dx = wd.dxv[u], dy = wd.dyv[u];
                float2 vdj = vd[wd.jv[u]];
                float wq = wendland_dkdq(q);
                float t  = q * wq * INV_H2;
                float s  = -2.f * vdj.x * t;
                float w2 = wq * INV_H3;
                float gwx = dx * w2, gwy = dy * w2;
                float rx = -dx * q * H, ry = -dy * q * H;
                float rji2 = rx * rx + ry * ry + EPS_REF;
                float gT = -t / rji2;
                float gv = gT * vdj.x;
                float rho_ba = REST_RHO * (vdj.y - vdl[li].y);
                k[u] = li;
                v[u][0] = s * dx * dx; v[u][1] = s * dx * dy; v[u][2] = s * dy * dy;
                v[u][3] = rho_ba * gv; v[u][4] = rx * gv;    v[u][5] = ry * gv;
                cst[e0 + u] = __floats2half2_rn(0.5f * rx * gv, 0.5f * ry * gv);
            }
        }
        seg_reduce4<6>(k, v, acc6);
    }
    __syncthreads();

    // ---- pinv (one lane per node), JAX cutoff semantics ----
    if (tid < NPB) {
        float a = acc6[6*tid], b = acc6[6*tid+1], cc = acc6[6*tid+2];
        float half_tr   = 0.5f * (a + cc);
        float half_diff = 0.5f * (a - cc);
        float disc = sqrtf(half_diff * half_diff + b * b);
        float l1 = half_tr + disc, l2 = half_tr - disc;
        float smax = fmaxf(fabsf(l1), fabsf(l2));
        float cutoff = 2.3841858e-6f * smax;   // rcond = 10*max(2,2)*eps_f32
        float i00 = 0.f, i01 = 0.f, i11 = 0.f;
        if (fabsf(l2) > cutoff) {
            float inv = 1.0f / (a * cc - b * b);
            i00 =  cc * inv; i01 = -b * inv; i11 = a * inv;
        } else if (fabsf(l1) > cutoff) {
            float vax = b,       vay = l1 - a;
            float vbx = l1 - cc, vby = b;
            float na = vax*vax + vay*vay, nb = vbx*vbx + vby*vby;
            float vx, vy, n2;
            if (nb >= na) { vx = vbx; vy = vby; n2 = nb; }
            else          { vx = vax; vy = vay; n2 = na; }
            float inv = 1.0f / (l1 * n2);
            i00 = vx*vx*inv; i01 = vx*vy*inv; i11 = vy*vy*inv;
        }
        Lild[3*tid] = i00; Lild[3*tid+1] = i01; Lild[3*tid+2] = i11;
    }
    __syncthreads();

    // ---- phase C: gradRho from stash ----
#pragma unroll
    for (int c = 0; c < SMAX; ++c) {
        long ebw = beg4 + ((long)c * BLOCKT + waveBase) * 4;
        if (ebw < (long)end) {
            int k[4]; float v[4][2];
#pragma unroll
            for (int u = 0; u < 4; ++u) {
                int li = li_s[c*4+u];
                k[u] = li; v[u][0] = v[u][1] = 0.f;
                if (li >= 0) {
                    float gwx = gwx_s[c*4+u], gwy = gwy_s[c*4+u];
                    float L0 = Lild[3*li], L1 = Lild[3*li+1], L2v = Lild[3*li+2];
                    float gx = L0 * gwx + L1 * gwy;
                    float gy = L1 * gwx + L2v * gwy;
                    float dm = fabsf(gwx) + fabsf(gwy);
                    float nm = fabsf(gx) + fabsf(gy);
                    float change = fabsf(nm - dm) / (dm + 1e-4f * H);
                    if (!(change < 0.1f)) { gx = gwx; gy = gwy; }   // NaN -> fallback
                    v[u][0] = val_s[c*4+u] * gx;
                    v[u][1] = val_s[c*4+u] * gy;
                }
            }
            seg_reduce4<2>(k, v, gld);
        }
    }
    for (int c = SMAX; ; ++c) {   // overflow recompute (rare)
        long ebw = beg4 + ((long)c * BLOCKT + waveBase) * 4;
        if (ebw >= (long)end) break;
        long e0 = beg4 + ((long)c * BLOCKT + tid) * 4;
        EW wd; load_win(e0, beg, end, E, ej, qarr, dirs, key8, wd);
        int k[4]; float v[4][2];
#pragma unroll
        for (int u = 0; u < 4; ++u) {
            k[u] = -1; v[u][0] = v[u][1] = 0.f;
            if (wd.okv[u]) {
                int li = wd.kv[u];
                float q = wd.qv[u], dx = wd.dxv[u], dy = wd.dyv[u];
                float2 vdj = vd[wd.jv[u]];
                float w2 = wendland_dkdq(q) * INV_H3;
                float gwx = dx * w2, gwy = dy * w2;
                float L0 = Lild[3*li], L1 = Lild[3*li+1], L2v = Lild[3*li+2];
                float gx = L0 * gwx + L1 * gwy;
                float gy = L1 * gwx + L2v * gwy;
                float dm = fabsf(gwx) + fabsf(gwy);
                float nm = fabsf(gx) + fabsf(gy);
                float change = fabsf(nm - dm) / (dm + 1e-4f * H);
                if (!(change < 0.1f)) { gx = gwx; gy = gwy; }
                float val = 2.f * REST_RHO * (vdj.y - vdl[li].y) * vdj.x;
                k[u] = li; v[u][0] = val * gx; v[u][1] = val * gy;
            }
        }
        seg_reduce4<2>(k, v, gld);
    }
    __syncthreads();
    if (tid < NPB && n0 + tid < N) {
        float gx = gld[2*tid], gy = gld[2*tid+1];
        g2[n0 + tid]   = make_float2(gx, gy);
        outp[n0 + tid] = acc6[6*tid+3] + 0.5f * (gx * acc6[6*tid+4] + gy * acc6[6*tid+5]);
    }
}

// Pass D (term 3 only): out = K_OUT * (outp + sum_e <g[j], c_e>).
// R8-proven windowed body; only launch_bounds changed 4->8.
__global__ __launch_bounds__(BLOCKT, 8)
void k_D(const int* __restrict__ ej, const unsigned char* __restrict__ key8,
         const __half2* __restrict__ cst,
         const float2* __restrict__ g2, const float* __restrict__ outp,
         const int* __restrict__ rowptr, float* __restrict__ out, int N, int E) {
    __shared__ float outl[NPB];
    const int tid = threadIdx.x;
    const int n0  = blockIdx.x * NPB;
    const int nHi = min(n0 + NPB, N);
    if (tid < NPB) outl[tid] = 0.f;
    __syncthreads();
    const int  beg = rowptr[n0], end = rowptr[nHi];
    const long beg4 = (long)beg & ~3L;
    const int  waveBase = tid & ~(WAVE - 1);

    for (int c = 0; ; ++c) {
        long ebw = beg4 + ((long)c * BLOCKT + waveBase) * 4;
        if (ebw >= (long)end) break;
        long e0 = beg4 + ((long)c * BLOCKT + tid) * 4;
        int jv[4], kv[4]; float cv[4]; bool okv[4];
        if (e0 + 3 < (long)E) {
            int4   j4 = *(const int4*)(ej + e0);
            float4 c4 = ((const float4*)cst)[e0 >> 2];
            uchar4 kk = *(const uchar4*)(key8 + e0);
            jv[0]=j4.x; jv[1]=j4.y; jv[2]=j4.z; jv[3]=j4.w;
            cv[0]=c4.x; cv[1]=c4.y; cv[2]=c4.z; cv[3]=c4.w;
            kv[0]=kk.x; kv[1]=kk.y; kv[2]=kk.z; kv[3]=kk.w;
        } else {
#pragma unroll
            for (int u = 0; u < 4; ++u) {
                long e = e0 + u;
                if (e < (long)E) { jv[u] = ej[e]; cv[u] = h2_as_f(cst[e]); kv[u] = key8[e]; }
                else             { jv[u] = 0;     cv[u] = 0.f;             kv[u] = 0; }
            }
        }
#pragma unroll
        for (int u = 0; u < 4; ++u) {
            long e = e0 + u;
            okv[u] = (e >= (long)beg) && (e < (long)end);
        }
        // all 4 gathers issued before use (R1-proven)
        float2 gj4[4];
#pragma unroll
        for (int u = 0; u < 4; ++u)
            gj4[u] = okv[u] ? g2[jv[u]] : make_float2(0.f, 0.f);
        int k[4]; float v[4][1];
#pragma unroll
        for (int u = 0; u < 4; ++u) {
            k[u] = -1; v[u][0] = 0.f;
            if (okv[u]) {
                __half2 ch = f_as_h2(cv[u]);
                k[u] = kv[u];                          // direct key
                v[u][0] = gj4[u].x * __low2float(ch) + gj4[u].y * __high2float(ch);
            }
        }
        seg_reduce4<1>(k, v, outl);
    }
    __syncthreads();
    if (tid < NPB && n0 + tid < N)
        out[n0 + tid] = K_OUT * (outp[n0 + tid] + outl[tid]);
}

extern "C" void kernel_launch(void* const* d_in, const int* in_sizes, int n_in,
                              void* d_out, int out_size, void* d_ws, size_t ws_size,
                              hipStream_t stream) {
    const float*  vol  = (const float*)d_in[1];
    const float*  dens = (const float*)d_in[2];
    const float2* dirs = (const float2*)d_in[3];
    const float*  qarr = (const float*)d_in[4];
    const int*    ei   = (const int*)d_in[5];
    const int*    ej   = (const int*)d_in[6];
    const int N = in_sizes[1];
    const int E = in_sizes[4];

    // ws: rowptr int[N+1] | vd f2[N] | g2 f2[N] | outp f[N] | cst h2[E] | key8 u8[E]
    size_t off = 0;
    auto alloc = [&](size_t bytes) { void* r = (char*)d_ws + off;
                                     off = (off + bytes + 15) & ~(size_t)15; return r; };
    int*           rowptr = (int*)          alloc((size_t)(N + 1) * 4);
    float2*        vd     = (float2*)       alloc((size_t)N * 8);
    float2*        g2     = (float2*)       alloc((size_t)N * 8);
    float*         outp   = (float*)        alloc((size_t)N * 4);
    __half2*       cst    = (__half2*)      alloc((size_t)E * 4);
    unsigned char* key8   = (unsigned char*)alloc((size_t)E);
    float*         out    = (float*)d_out;

    const int tb = 256;
    const int gP = (E + 1 + tb - 1) / tb;
    const int gB = (N + NPB - 1) / NPB;

    k_prep<<<gP, tb, 0, stream>>>(ei, vol, dens, rowptr, vd, key8, N, E);
    k_AC  <<<gB, BLOCKT, 0, stream>>>(ej, qarr, dirs, vd, rowptr, key8, cst, g2, outp, N, E);
    k_D   <<<gB, BLOCKT, 0, stream>>>(ej, key8, cst, g2, outp, rowptr, out, N, E);
}

// Round 11
// 243.726 us; speedup vs baseline: 1.6283x; 1.6283x over previous
//
#include <hip/hip_runtime.h>
#include <hip/hip_fp16.h>
#include <math.h>

#define WAVE   64
#define NPB    32          // k_AC nodes per window (key low 5 bits)
#define NPBD   128         // k_D nodes per window (key full 7 bits)
#define BLOCKT 256
#define SMAX   2           // stashed 1024-edge chunks (covers <=2048 edges/window)

// ---- constants from the reference ----
#define KC        2.2281692032865347f   // 7/pi
#define H         0.05f
#define INV_H2    400.0f
#define INV_H3    8000.0f
#define EPS_REF   0.00025f              // h^2 * 0.1
#define K_OUT     0.24261080f           // 2*h*DELTA*C0
#define REST_RHO  1000.0f

__device__ __forceinline__ float wendland_dkdq(float q) {
    float o = 1.f - q;
    return -20.f * q * o * o * o * KC;
}

union H2F { __half2 h; float f; };
__device__ __forceinline__ float   h2_as_f(__half2 h) { H2F u; u.h = h; return u.f; }
__device__ __forceinline__ __half2 f_as_h2(float f)   { H2F u; u.f = f; return u.h; }

// ---------------------------------------------------------------------------
// 4-edge-per-lane segmented reduction via shuffle scan (R0-proven).
// Equal keys contiguous in lane order; key<0 skipped. base may be LDS.
// Scan capped at d<=16 (reach 31 lanes; runs up to ~124 edges OK; degrees
// ~Poisson(32), max ~60 -> 2x margin). Correctness-proven R1/R3/R4/R8.
// ---------------------------------------------------------------------------
template<int NV>
__device__ __forceinline__ void seg_reduce4(const int k[4], float v[4][NV], float* base) {
    const int lane = threadIdx.x & (WAVE - 1);
    const int k0 = k[0], k3 = k[3];
    const bool split = (k0 != k3);
    const int firstLen  = (k[1]==k0) ? ((k[2]==k0) ? ((k[3]==k0)?4:3) : 2) : 1;
    const int lastStart = (k[2]==k3) ? ((k[1]==k3) ? ((k[0]==k3)?0:1) : 2) : 3;

    float vin[NV], vfirst[NV];
#pragma unroll
    for (int c = 0; c < NV; ++c) {
        float s = v[3][c];
        if (lastStart <= 2) s += v[2][c];
        if (lastStart <= 1) s += v[1][c];
        if (lastStart == 0) s += v[0][c];
        vin[c] = s;
        float f = v[0][c];
        if (firstLen >= 2) f += v[1][c];
        if (firstLen >= 3) f += v[2][c];
        if (firstLen >= 4) f += v[3][c];
        vfirst[c] = f;
    }
#pragma unroll
    for (int idx = 1; idx <= 2; ++idx) {
        if (idx >= firstLen && idx < lastStart && k[idx] >= 0) {
#pragma unroll
            for (int c = 0; c < NV; ++c)
                atomicAdd(base + (size_t)k[idx] * NV + c, v[idx][c]);
        }
    }
    float S[NV];
#pragma unroll
    for (int c = 0; c < NV; ++c) S[c] = vin[c];
    const int klast = k3;
#pragma unroll
    for (int d = 1; d <= 16; d <<= 1) {   // 5 steps (bound above)
        int okey = __shfl_up(klast, d, WAVE);
        float ov[NV];
#pragma unroll
        for (int c = 0; c < NV; ++c) ov[c] = __shfl_up(S[c], d, WAVE);
        if (lane >= d && okey == klast) {
#pragma unroll
            for (int c = 0; c < NV; ++c) S[c] += ov[c];
        }
    }
    const int prevk = __shfl_up(klast, 1, WAVE);
    float P[NV];
#pragma unroll
    for (int c = 0; c < NV; ++c) P[c] = __shfl_up(S[c], 1, WAVE);
    if (split && k0 >= 0) {
        const bool carry = (lane > 0 && prevk == k0);
#pragma unroll
        for (int c = 0; c < NV; ++c)
            atomicAdd(base + (size_t)k0 * NV + c, vfirst[c] + (carry ? P[c] : 0.f));
    }
    const int nk0 = __shfl_down(k0, 1, WAVE);
    const bool tail = (lane == WAVE - 1) || (nk0 != klast);
    if (tail && klast >= 0) {
#pragma unroll
        for (int c = 0; c < NV; ++c)
            atomicAdd(base + (size_t)klast * NV + c, S[c]);
    }
}

struct EW { int jv[4]; float qv[4], dxv[4], dyv[4]; int kv[4]; bool okv[4]; };

// loads 4 edges + their precomputed 8-bit window keys (ei & 127)
__device__ __forceinline__ void load_win(long e0, int beg, int end, int E,
        const int* __restrict__ ej, const float* __restrict__ qarr,
        const float2* __restrict__ dirs, const unsigned char* __restrict__ key8,
        EW& w) {
    if (e0 + 3 < (long)E) {
        int4   j4 = *(const int4*)(ej + e0);
        float4 q4 = *(const float4*)(qarr + e0);
        float4 dA = *(const float4*)((const float*)dirs + 2 * e0);
        float4 dB = *(const float4*)((const float*)dirs + 2 * e0 + 4);
        uchar4 kk = *(const uchar4*)(key8 + e0);
        w.jv[0]=j4.x; w.jv[1]=j4.y; w.jv[2]=j4.z; w.jv[3]=j4.w;
        w.qv[0]=q4.x; w.qv[1]=q4.y; w.qv[2]=q4.z; w.qv[3]=q4.w;
        w.dxv[0]=dA.x; w.dyv[0]=dA.y; w.dxv[1]=dA.z; w.dyv[1]=dA.w;
        w.dxv[2]=dB.x; w.dyv[2]=dB.y; w.dxv[3]=dB.z; w.dyv[3]=dB.w;
        w.kv[0]=kk.x; w.kv[1]=kk.y; w.kv[2]=kk.z; w.kv[3]=kk.w;
    } else {
#pragma unroll
        for (int u = 0; u < 4; ++u) {
            long e = e0 + u;
            if (e < (long)E) {
                w.jv[u] = ej[e]; w.qv[u] = qarr[e]; w.kv[u] = key8[e];
                float2 d = dirs[e]; w.dxv[u] = d.x; w.dyv[u] = d.y;
            } else { w.jv[u]=0; w.qv[u]=0.f; w.dxv[u]=0.f; w.dyv[u]=0.f; w.kv[u]=0; }
        }
    }
#pragma unroll
    for (int u = 0; u < 4; ++u) {
        long e = e0 + u;
        w.okv[u] = (e >= (long)beg) && (e < (long)end);
    }
}

// rowptr[t]=first edge with i>=t; vd=(vol,dens); key8[e]=ei[e]&127
__global__ void k_prep(const int* __restrict__ ei, const float* __restrict__ vol,
                       const float* __restrict__ dens, int* __restrict__ rowptr,
                       float2* __restrict__ vd, unsigned char* __restrict__ key8,
                       int N, int E) {
    int e = blockIdx.x * blockDim.x + threadIdx.x;
    if (e <= E) {
        int prev = (e == 0) ? -1 : ei[e - 1];
        int cur  = (e == E) ? N  : ei[e];
        for (int t = prev + 1; t <= cur; ++t) rowptr[t] = e;
        if (e < E) key8[e] = (unsigned char)(cur & (NPBD - 1));
    }
    if (e < N) vd[e] = make_float2(vol[e], dens[e]);
}

// Fused A+B+C+term1/2 of D (R8-proven body; li = key & 31).
__global__ __launch_bounds__(BLOCKT, 4)
void k_AC(const int* __restrict__ ej, const float* __restrict__ qarr,
          const float2* __restrict__ dirs, const float2* __restrict__ vd,
          const int* __restrict__ rowptr, const unsigned char* __restrict__ key8,
          __half2* __restrict__ cst,
          float2* __restrict__ g2, float* __restrict__ outp, int N, int E) {
    __shared__ float  acc6[NPB * 6];     // m00,m01,m11,A,Bx,By
    __shared__ float  Lild[NPB * 3];
    __shared__ float  gld[NPB * 2];
    __shared__ float2 vdl[NPB];
    const int tid = threadIdx.x;
    const int n0  = blockIdx.x * NPB;
    const int nHi = min(n0 + NPB, N);
    if (tid < NPB && n0 + tid < N) vdl[tid] = vd[n0 + tid];
    if (tid < NPB * 6) acc6[tid] = 0.f;
    if (tid < NPB * 2) gld[tid] = 0.f;
    __syncthreads();
    const int  beg = rowptr[n0], end = rowptr[nHi];   // uniform -> scalar loads
    const long beg4 = (long)beg & ~3L;
    const int  waveBase = tid & ~(WAVE - 1);

    int   li_s[4 * SMAX];
    float gwx_s[4 * SMAX], gwy_s[4 * SMAX], val_s[4 * SMAX];
#pragma unroll
    for (int x = 0; x < 4 * SMAX; ++x) { li_s[x] = -1; gwx_s[x]=gwy_s[x]=val_s[x]=0.f; }

    // ---- phase A ----
#pragma unroll
    for (int c = 0; c < SMAX; ++c) {
        long ebw = beg4 + ((long)c * BLOCKT + waveBase) * 4;
        if (ebw < (long)end) {
            long e0 = beg4 + ((long)c * BLOCKT + tid) * 4;
            EW wd; load_win(e0, beg, end, E, ej, qarr, dirs, key8, wd);
            const bool all4 = wd.okv[0] && wd.okv[1] && wd.okv[2] && wd.okv[3];
            float4 cpack;
            int k[4]; float v[4][6];
#pragma unroll
            for (int u = 0; u < 4; ++u) {
                k[u] = -1;
#pragma unroll
                for (int c2 = 0; c2 < 6; ++c2) v[u][c2] = 0.f;
                if (wd.okv[u]) {
                    int li = wd.kv[u] & (NPB - 1);     // low 5 bits of window key
                    float q = wd.qv[u], dx = wd.dxv[u], dy = wd.dyv[u];
                    float2 vdj = vd[wd.jv[u]];
                    float wq = wendland_dkdq(q);
                    float t  = q * wq * INV_H2;        // unit dirs: gw.r_ba = -t
                    float s  = -2.f * vdj.x * t;       // >= 0
                    float w2 = wq * INV_H3;
                    float gwx = dx * w2, gwy = dy * w2;
                    float rx = -dx * q * H, ry = -dy * q * H;
                    float rji2 = rx * rx + ry * ry + EPS_REF;
                    float gT = -t / rji2;
                    float gv = gT * vdj.x;
                    float rho_ba = REST_RHO * (vdj.y - vdl[li].y);
                    k[u] = li;
                    v[u][0] = s * dx * dx; v[u][1] = s * dx * dy; v[u][2] = s * dy * dy;
                    v[u][3] = rho_ba * gv; v[u][4] = rx * gv;    v[u][5] = ry * gv;
                    __half2 cp = __floats2half2_rn(0.5f * rx * gv, 0.5f * ry * gv);
                    if (all4) (&cpack.x)[u] = h2_as_f(cp);
                    else      cst[e0 + u] = cp;
                    li_s[c*4+u] = li; gwx_s[c*4+u] = gwx; gwy_s[c*4+u] = gwy;
                    val_s[c*4+u] = 2.f * rho_ba * vdj.x;
                }
            }
            if (all4) ((float4*)cst)[e0 >> 2] = cpack;
            seg_reduce4<6>(k, v, acc6);
        }
    }
    // overflow (window > SMAX*1024 edges; practically never at avg degree 32)
    for (int c = SMAX; ; ++c) {
        long ebw = beg4 + ((long)c * BLOCKT + waveBase) * 4;
        if (ebw >= (long)end) break;
        long e0 = beg4 + ((long)c * BLOCKT + tid) * 4;
        EW wd; load_win(e0, beg, end, E, ej, qarr, dirs, key8, wd);
        int k[4]; float v[4][6];
#pragma unroll
        for (int u = 0; u < 4; ++u) {
            k[u] = -1;
#pragma unroll
            for (int c2 = 0; c2 < 6; ++c2) v[u][c2] = 0.f;
            if (wd.okv[u]) {
                int li = wd.kv[u] & (NPB - 1);
                float q = wd.qv[u], dx = wd.dxv[u], dy = wd.dyv[u];
                float2 vdj = vd[wd.jv[u]];
                float wq = wendland_dkdq(q);
                float t  = q * wq * INV_H2;
                float s  = -2.f * vdj.x * t;
                float w2 = wq * INV_H3;
                float gwx = dx * w2, gwy = dy * w2;
                float rx = -dx * q * H, ry = -dy * q * H;
                float rji2 = rx * rx + ry * ry + EPS_REF;
                float gT = -t / rji2;
                float gv = gT * vdj.x;
                float rho_ba = REST_RHO * (vdj.y - vdl[li].y);
                k[u] = li;
                v[u][0] = s * dx * dx; v[u][1] = s * dx * dy; v[u][2] = s * dy * dy;
                v[u][3] = rho_ba * gv; v[u][4] = rx * gv;    v[u][5] = ry * gv;
                cst[e0 + u] = __floats2half2_rn(0.5f * rx * gv, 0.5f * ry * gv);
            }
        }
        seg_reduce4<6>(k, v, acc6);
    }
    __syncthreads();

    // ---- pinv (one lane per node), JAX cutoff semantics ----
    if (tid < NPB) {
        float a = acc6[6*tid], b = acc6[6*tid+1], cc = acc6[6*tid+2];
        float half_tr   = 0.5f * (a + cc);
        float half_diff = 0.5f * (a - cc);
        float disc = sqrtf(half_diff * half_diff + b * b);
        float l1 = half_tr + disc, l2 = half_tr - disc;
        float smax = fmaxf(fabsf(l1), fabsf(l2));
        float cutoff = 2.3841858e-6f * smax;   // rcond = 10*max(2,2)*eps_f32
        float i00 = 0.f, i01 = 0.f, i11 = 0.f;
        if (fabsf(l2) > cutoff) {
            float inv = 1.0f / (a * cc - b * b);
            i00 =  cc * inv; i01 = -b * inv; i11 = a * inv;
        } else if (fabsf(l1) > cutoff) {
            float vax = b,       vay = l1 - a;
            float vbx = l1 - cc, vby = b;
            float na = vax*vax + vay*vay, nb = vbx*vbx + vby*vby;
            float vx, vy, n2;
            if (nb >= na) { vx = vbx; vy = vby; n2 = nb; }
            else          { vx = vax; vy = vay; n2 = na; }
            float inv = 1.0f / (l1 * n2);
            i00 = vx*vx*inv; i01 = vx*vy*inv; i11 = vy*vy*inv;
        }
        Lild[3*tid] = i00; Lild[3*tid+1] = i01; Lild[3*tid+2] = i11;
    }
    __syncthreads();

    // ---- phase C: gradRho from stash ----
#pragma unroll
    for (int c = 0; c < SMAX; ++c) {
        long ebw = beg4 + ((long)c * BLOCKT + waveBase) * 4;
        if (ebw < (long)end) {
            int k[4]; float v[4][2];
#pragma unroll
            for (int u = 0; u < 4; ++u) {
                int li = li_s[c*4+u];
                k[u] = li; v[u][0] = v[u][1] = 0.f;
                if (li >= 0) {
                    float gwx = gwx_s[c*4+u], gwy = gwy_s[c*4+u];
                    float L0 = Lild[3*li], L1 = Lild[3*li+1], L2v = Lild[3*li+2];
                    float gx = L0 * gwx + L1 * gwy;
                    float gy = L1 * gwx + L2v * gwy;
                    float dm = fabsf(gwx) + fabsf(gwy);
                    float nm = fabsf(gx) + fabsf(gy);
                    float change = fabsf(nm - dm) / (dm + 1e-4f * H);
                    if (!(change < 0.1f)) { gx = gwx; gy = gwy; }   // NaN -> fallback
                    v[u][0] = val_s[c*4+u] * gx;
                    v[u][1] = val_s[c*4+u] * gy;
                }
            }
            seg_reduce4<2>(k, v, gld);
        }
    }
    for (int c = SMAX; ; ++c) {   // overflow recompute (rare)
        long ebw = beg4 + ((long)c * BLOCKT + waveBase) * 4;
        if (ebw >= (long)end) break;
        long e0 = beg4 + ((long)c * BLOCKT + tid) * 4;
        EW wd; load_win(e0, beg, end, E, ej, qarr, dirs, key8, wd);
        int k[4]; float v[4][2];
#pragma unroll
        for (int u = 0; u < 4; ++u) {
            k[u] = -1; v[u][0] = v[u][1] = 0.f;
            if (wd.okv[u]) {
                int li = wd.kv[u] & (NPB - 1);
                float q = wd.qv[u], dx = wd.dxv[u], dy = wd.dyv[u];
                float2 vdj = vd[wd.jv[u]];
                float w2 = wendland_dkdq(q) * INV_H3;
                float gwx = dx * w2, gwy = dy * w2;
                float L0 = Lild[3*li], L1 = Lild[3*li+1], L2v = Lild[3*li+2];
                float gx = L0 * gwx + L1 * gwy;
                float gy = L1 * gwx + L2v * gwy;
                float dm = fabsf(gwx) + fabsf(gwy);
                float nm = fabsf(gx) + fabsf(gy);
                float change = fabsf(nm - dm) / (dm + 1e-4f * H);
                if (!(change < 0.1f)) { gx = gwx; gy = gwy; }
                float val = 2.f * REST_RHO * (vdj.y - vdl[li].y) * vdj.x;
                k[u] = li; v[u][0] = val * gx; v[u][1] = val * gy;
            }
        }
        seg_reduce4<2>(k, v, gld);
    }
    __syncthreads();
    if (tid < NPB && n0 + tid < N) {
        float gx = gld[2*tid], gy = gld[2*tid+1];
        g2[n0 + tid]   = make_float2(gx, gy);
        outp[n0 + tid] = acc6[6*tid+3] + 0.5f * (gx * acc6[6*tid+4] + gy * acc6[6*tid+5]);
    }
}

// Pass D (term 3 only): out = K_OUT * (outp + sum_e <g[j], c_e>).
// R8 body, widened to NPBD=128 nodes/window (~4 chunks per wave, looped ->
// loads of chunk c+1 overlap the scan of chunk c; 4x fewer blocks).
__global__ __launch_bounds__(BLOCKT, 4)
void k_D(const int* __restrict__ ej, const unsigned char* __restrict__ key8,
         const __half2* __restrict__ cst,
         const float2* __restrict__ g2, const float* __restrict__ outp,
         const int* __restrict__ rowptr, float* __restrict__ out, int N, int E) {
    __shared__ float outl[NPBD];
    const int tid = threadIdx.x;
    const int n0  = blockIdx.x * NPBD;
    const int nHi = min(n0 + NPBD, N);
    if (tid < NPBD) outl[tid] = 0.f;
    __syncthreads();
    const int  beg = rowptr[n0], end = rowptr[nHi];
    const long beg4 = (long)beg & ~3L;
    const int  waveBase = tid & ~(WAVE - 1);

    for (int c = 0; ; ++c) {
        long ebw = beg4 + ((long)c * BLOCKT + waveBase) * 4;
        if (ebw >= (long)end) break;
        long e0 = beg4 + ((long)c * BLOCKT + tid) * 4;
        int jv[4], kv[4]; float cv[4]; bool okv[4];
        if (e0 + 3 < (long)E) {
            int4   j4 = *(const int4*)(ej + e0);
            float4 c4 = ((const float4*)cst)[e0 >> 2];
            uchar4 kk = *(const uchar4*)(key8 + e0);
            jv[0]=j4.x; jv[1]=j4.y; jv[2]=j4.z; jv[3]=j4.w;
            cv[0]=c4.x; cv[1]=c4.y; cv[2]=c4.z; cv[3]=c4.w;
            kv[0]=kk.x; kv[1]=kk.y; kv[2]=kk.z; kv[3]=kk.w;
        } else {
#pragma unroll
            for (int u = 0; u < 4; ++u) {
                long e = e0 + u;
                if (e < (long)E) { jv[u] = ej[e]; cv[u] = h2_as_f(cst[e]); kv[u] = key8[e]; }
                else             { jv[u] = 0;     cv[u] = 0.f;             kv[u] = 0; }
            }
        }
#pragma unroll
        for (int u = 0; u < 4; ++u) {
            long e = e0 + u;
            okv[u] = (e >= (long)beg) && (e < (long)end);
        }
        // all 4 gathers issued before use (R1-proven)
        float2 gj4[4];
#pragma unroll
        for (int u = 0; u < 4; ++u)
            gj4[u] = okv[u] ? g2[jv[u]] : make_float2(0.f, 0.f);
        int k[4]; float v[4][1];
#pragma unroll
        for (int u = 0; u < 4; ++u) {
            k[u] = -1; v[u][0] = 0.f;
            if (okv[u]) {
                __half2 ch = f_as_h2(cv[u]);
                k[u] = kv[u];                          // direct 7-bit key
                v[u][0] = gj4[u].x * __low2float(ch) + gj4[u].y * __high2float(ch);
            }
        }
        seg_reduce4<1>(k, v, outl);
    }
    __syncthreads();
    if (tid < NPBD && n0 + tid < N)
        out[n0 + tid] = K_OUT * (outp[n0 + tid] + outl[tid]);
}

extern "C" void kernel_launch(void* const* d_in, const int* in_sizes, int n_in,
                              void* d_out, int out_size, void* d_ws, size_t ws_size,
                              hipStream_t stream) {
    const float*  vol  = (const float*)d_in[1];
    const float*  dens = (const float*)d_in[2];
    const float2* dirs = (const float2*)d_in[3];
    const float*  qarr = (const float*)d_in[4];
    const int*    ei   = (const int*)d_in[5];
    const int*    ej   = (const int*)d_in[6];
    const int N = in_sizes[1];
    const int E = in_sizes[4];

    // ws: rowptr int[N+1] | vd f2[N] | g2 f2[N] | outp f[N] | cst h2[E] | key8 u8[E]
    size_t off = 0;
    auto alloc = [&](size_t bytes) { void* r = (char*)d_ws + off;
                                     off = (off + bytes + 15) & ~(size_t)15; return r; };
    int*           rowptr = (int*)          alloc((size_t)(N + 1) * 4);
    float2*        vd     = (float2*)       alloc((size_t)N * 8);
    float2*        g2     = (float2*)       alloc((size_t)N * 8);
    float*         outp   = (float*)        alloc((size_t)N * 4);
    __half2*       cst    = (__half2*)      alloc((size_t)E * 4);
    unsigned char* key8   = (unsigned char*)alloc((size_t)E);
    float*         out    = (float*)d_out;

    const int tb = 256;
    const int gP = (E + 1 + tb - 1) / tb;
    const int gB = (N + NPB - 1) / NPB;
    const int gD = (N + NPBD - 1) / NPBD;

    k_prep<<<gP, tb, 0, stream>>>(ei, vol, dens, rowptr, vd, key8, N, E);
    k_AC  <<<gB, BLOCKT, 0, stream>>>(ej, qarr, dirs, vd, rowptr, key8, cst, g2, outp, N, E);
    k_D   <<<gD, BLOCKT, 0, stream>>>(ej, key8, cst, g2, outp, rowptr, out, N, E);
}

// Round 12
// 239.280 us; speedup vs baseline: 1.6586x; 1.0186x over previous
//
#include <hip/hip_runtime.h>
#include <hip/hip_fp16.h>
#include <math.h>

#define WAVE   64
#define NPB    64          // k_AC nodes per window (key low 6 bits)
#define NPBD   128         // k_D nodes per window (key full 7 bits)
#define BT_AC  512         // k_AC block: 2048-edge chunk = avg window
#define BT_D   256
#define SMAX   1           // stashed chunks (avg window = exactly 1 chunk)

// ---- constants from the reference ----
#define KC        2.2281692032865347f   // 7/pi
#define H         0.05f
#define INV_H2    400.0f
#define INV_H3    8000.0f
#define EPS_REF   0.00025f              // h^2 * 0.1
#define K_OUT     0.24261080f           // 2*h*DELTA*C0
#define REST_RHO  1000.0f

__device__ __forceinline__ float wendland_dkdq(float q) {
    float o = 1.f - q;
    return -20.f * q * o * o * o * KC;
}

union H2F { __half2 h; float f; };
__device__ __forceinline__ float   h2_as_f(__half2 h) { H2F u; u.h = h; return u.f; }
__device__ __forceinline__ __half2 f_as_h2(float f)   { H2F u; u.f = f; return u.h; }

// ---------------------------------------------------------------------------
// 4-edge-per-lane segmented reduction via shuffle scan (R0-proven).
// Equal keys contiguous in lane order; key<0 skipped. base may be LDS.
// Scan capped at d<=16 (reach 31 lanes; runs up to ~124 edges OK; degrees
// ~Poisson(32), max ~60 -> 2x margin). Correctness-proven R1/R3/R4/R8/R11.
// ---------------------------------------------------------------------------
template<int NV>
__device__ __forceinline__ void seg_reduce4(const int k[4], float v[4][NV], float* base) {
    const int lane = threadIdx.x & (WAVE - 1);
    const int k0 = k[0], k3 = k[3];
    const bool split = (k0 != k3);
    const int firstLen  = (k[1]==k0) ? ((k[2]==k0) ? ((k[3]==k0)?4:3) : 2) : 1;
    const int lastStart = (k[2]==k3) ? ((k[1]==k3) ? ((k[0]==k3)?0:1) : 2) : 3;

    float vin[NV], vfirst[NV];
#pragma unroll
    for (int c = 0; c < NV; ++c) {
        float s = v[3][c];
        if (lastStart <= 2) s += v[2][c];
        if (lastStart <= 1) s += v[1][c];
        if (lastStart == 0) s += v[0][c];
        vin[c] = s;
        float f = v[0][c];
        if (firstLen >= 2) f += v[1][c];
        if (firstLen >= 3) f += v[2][c];
        if (firstLen >= 4) f += v[3][c];
        vfirst[c] = f;
    }
#pragma unroll
    for (int idx = 1; idx <= 2; ++idx) {
        if (idx >= firstLen && idx < lastStart && k[idx] >= 0) {
#pragma unroll
            for (int c = 0; c < NV; ++c)
                atomicAdd(base + (size_t)k[idx] * NV + c, v[idx][c]);
        }
    }
    float S[NV];
#pragma unroll
    for (int c = 0; c < NV; ++c) S[c] = vin[c];
    const int klast = k3;
#pragma unroll
    for (int d = 1; d <= 16; d <<= 1) {   // 5 steps (bound above)
        int okey = __shfl_up(klast, d, WAVE);
        float ov[NV];
#pragma unroll
        for (int c = 0; c < NV; ++c) ov[c] = __shfl_up(S[c], d, WAVE);
        if (lane >= d && okey == klast) {
#pragma unroll
            for (int c = 0; c < NV; ++c) S[c] += ov[c];
        }
    }
    const int prevk = __shfl_up(klast, 1, WAVE);
    float P[NV];
#pragma unroll
    for (int c = 0; c < NV; ++c) P[c] = __shfl_up(S[c], 1, WAVE);
    if (split && k0 >= 0) {
        const bool carry = (lane > 0 && prevk == k0);
#pragma unroll
        for (int c = 0; c < NV; ++c)
            atomicAdd(base + (size_t)k0 * NV + c, vfirst[c] + (carry ? P[c] : 0.f));
    }
    const int nk0 = __shfl_down(k0, 1, WAVE);
    const bool tail = (lane == WAVE - 1) || (nk0 != klast);
    if (tail && klast >= 0) {
#pragma unroll
        for (int c = 0; c < NV; ++c)
            atomicAdd(base + (size_t)klast * NV + c, S[c]);
    }
}

struct EW { int jv[4]; float qv[4], dxv[4], dyv[4]; int kv[4]; bool okv[4]; };

// loads 4 edges + their precomputed 8-bit window keys (ei & 127)
__device__ __forceinline__ void load_win(long e0, int beg, int end, int E,
        const int* __restrict__ ej, const float* __restrict__ qarr,
        const float2* __restrict__ dirs, const unsigned char* __restrict__ key8,
        EW& w) {
    if (e0 + 3 < (long)E) {
        int4   j4 = *(const int4*)(ej + e0);
        float4 q4 = *(const float4*)(qarr + e0);
        float4 dA = *(const float4*)((const float*)dirs + 2 * e0);
        float4 dB = *(const float4*)((const float*)dirs + 2 * e0 + 4);
        uchar4 kk = *(const uchar4*)(key8 + e0);
        w.jv[0]=j4.x; w.jv[1]=j4.y; w.jv[2]=j4.z; w.jv[3]=j4.w;
        w.qv[0]=q4.x; w.qv[1]=q4.y; w.qv[2]=q4.z; w.qv[3]=q4.w;
        w.dxv[0]=dA.x; w.dyv[0]=dA.y; w.dxv[1]=dA.z; w.dyv[1]=dA.w;
        w.dxv[2]=dB.x; w.dyv[2]=dB.y; w.dxv[3]=dB.z; w.dyv[3]=dB.w;
        w.kv[0]=kk.x; w.kv[1]=kk.y; w.kv[2]=kk.z; w.kv[3]=kk.w;
    } else {
#pragma unroll
        for (int u = 0; u < 4; ++u) {
            long e = e0 + u;
            if (e < (long)E) {
                w.jv[u] = ej[e]; w.qv[u] = qarr[e]; w.kv[u] = key8[e];
                float2 d = dirs[e]; w.dxv[u] = d.x; w.dyv[u] = d.y;
            } else { w.jv[u]=0; w.qv[u]=0.f; w.dxv[u]=0.f; w.dyv[u]=0.f; w.kv[u]=0; }
        }
    }
#pragma unroll
    for (int u = 0; u < 4; ++u) {
        long e = e0 + u;
        w.okv[u] = (e >= (long)beg) && (e < (long)end);
    }
}

// Vectorized prep: 4 edges/thread (int4 ei, uchar4 key8) + 4 nodes/thread
// (float4 vol/dens -> 2x float4 vd stores). rowptr[t]=first edge with i>=t.
__global__ void k_prep(const int* __restrict__ ei, const float* __restrict__ vol,
                       const float* __restrict__ dens, int* __restrict__ rowptr,
                       float2* __restrict__ vd, unsigned char* __restrict__ key8,
                       int N, int E) {
    const long e0 = ((long)blockIdx.x * blockDim.x + threadIdx.x) * 4;
    if (e0 <= (long)E) {
        int prev = (e0 == 0) ? -1 : ei[e0 - 1];
        if (e0 + 3 < (long)E) {
            int4 c4 = *(const int4*)(ei + e0);
            uchar4 kk;
            int cur;
            cur = c4.x; for (int t = prev + 1; t <= cur; ++t) rowptr[t] = (int)e0;
            kk.x = (unsigned char)(cur & (NPBD - 1)); prev = cur;
            cur = c4.y; for (int t = prev + 1; t <= cur; ++t) rowptr[t] = (int)e0 + 1;
            kk.y = (unsigned char)(cur & (NPBD - 1)); prev = cur;
            cur = c4.z; for (int t = prev + 1; t <= cur; ++t) rowptr[t] = (int)e0 + 2;
            kk.z = (unsigned char)(cur & (NPBD - 1)); prev = cur;
            cur = c4.w; for (int t = prev + 1; t <= cur; ++t) rowptr[t] = (int)e0 + 3;
            kk.w = (unsigned char)(cur & (NPBD - 1)); prev = cur;
            *(uchar4*)(key8 + e0) = kk;
        } else {
#pragma unroll 4
            for (int u = 0; u < 4; ++u) {
                long e = e0 + u;
                if (e > (long)E) break;
                int cur = (e == (long)E) ? N : ei[e];
                for (int t = prev + 1; t <= cur; ++t) rowptr[t] = (int)e;
                if (e < (long)E) key8[e] = (unsigned char)(cur & (NPBD - 1));
                prev = cur;
            }
        }
    }
    if (e0 + 3 < (long)N) {
        float4 vv = *(const float4*)(vol + e0);
        float4 dd = *(const float4*)(dens + e0);
        ((float4*)vd)[(e0 >> 1)]     = make_float4(vv.x, dd.x, vv.y, dd.y);
        ((float4*)vd)[(e0 >> 1) + 1] = make_float4(vv.z, dd.z, vv.w, dd.w);
    } else {
        for (long n = e0; n < (long)N && n < e0 + 4; ++n)
            vd[n] = make_float2(vol[n], dens[n]);
    }
}

// Fused A+B+C+term1/2 of D (R8-proven body; NPB=64, BT_AC=512, SMAX=1:
// avg window == one chunk, stash halves, 2x fewer blocks; li = key & 63).
__global__ __launch_bounds__(BT_AC, 4)
void k_AC(const int* __restrict__ ej, const float* __restrict__ qarr,
          const float2* __restrict__ dirs, const float2* __restrict__ vd,
          const int* __restrict__ rowptr, const unsigned char* __restrict__ key8,
          __half2* __restrict__ cst,
          float2* __restrict__ g2, float* __restrict__ outp, int N, int E) {
    __shared__ float  acc6[NPB * 6];     // m00,m01,m11,A,Bx,By
    __shared__ float  Lild[NPB * 3];
    __shared__ float  gld[NPB * 2];
    __shared__ float2 vdl[NPB];
    const int tid = threadIdx.x;
    const int n0  = blockIdx.x * NPB;
    const int nHi = min(n0 + NPB, N);
    if (tid < NPB && n0 + tid < N) vdl[tid] = vd[n0 + tid];
    if (tid < NPB * 6) acc6[tid] = 0.f;
    if (tid < NPB * 2) gld[tid] = 0.f;
    __syncthreads();
    const int  beg = rowptr[n0], end = rowptr[nHi];   // uniform -> scalar loads
    const long beg4 = (long)beg & ~3L;
    const int  waveBase = tid & ~(WAVE - 1);

    int   li_s[4 * SMAX];
    float gwx_s[4 * SMAX], gwy_s[4 * SMAX], val_s[4 * SMAX];
#pragma unroll
    for (int x = 0; x < 4 * SMAX; ++x) { li_s[x] = -1; gwx_s[x]=gwy_s[x]=val_s[x]=0.f; }

    // ---- phase A (stashed chunk 0) ----
#pragma unroll
    for (int c = 0; c < SMAX; ++c) {
        long ebw = beg4 + ((long)c * BT_AC + waveBase) * 4;
        if (ebw < (long)end) {
            long e0 = beg4 + ((long)c * BT_AC + tid) * 4;
            EW wd; load_win(e0, beg, end, E, ej, qarr, dirs, key8, wd);
            const bool all4 = wd.okv[0] && wd.okv[1] && wd.okv[2] && wd.okv[3];
            float4 cpack;
            int k[4]; float v[4][6];
#pragma unroll
            for (int u = 0; u < 4; ++u) {
                k[u] = -1;
#pragma unroll
                for (int c2 = 0; c2 < 6; ++c2) v[u][c2] = 0.f;
                if (wd.okv[u]) {
                    int li = wd.kv[u] & (NPB - 1);     // low 6 bits of window key
                    float q = wd.qv[u], dx = wd.dxv[u], dy = wd.dyv[u];
                    float2 vdj = vd[wd.jv[u]];
                    float wq = wendland_dkdq(q);
                    float t  = q * wq * INV_H2;        // unit dirs: gw.r_ba = -t
                    float s  = -2.f * vdj.x * t;       // >= 0
                    float w2 = wq * INV_H3;
                    float gwx = dx * w2, gwy = dy * w2;
                    float rx = -dx * q * H, ry = -dy * q * H;
                    float rji2 = rx * rx + ry * ry + EPS_REF;
                    float gT = -t / rji2;
                    float gv = gT * vdj.x;
                    float rho_ba = REST_RHO * (vdj.y - vdl[li].y);
                    k[u] = li;
                    v[u][0] = s * dx * dx; v[u][1] = s * dx * dy; v[u][2] = s * dy * dy;
                    v[u][3] = rho_ba * gv; v[u][4] = rx * gv;    v[u][5] = ry * gv;
                    __half2 cp = __floats2half2_rn(0.5f * rx * gv, 0.5f * ry * gv);
                    if (all4) (&cpack.x)[u] = h2_as_f(cp);
                    else      cst[e0 + u] = cp;
                    li_s[c*4+u] = li; gwx_s[c*4+u] = gwx; gwy_s[c*4+u] = gwy;
                    val_s[c*4+u] = 2.f * rho_ba * vdj.x;
                }
            }
            if (all4) ((float4*)cst)[e0 >> 2] = cpack;
            seg_reduce4<6>(k, v, acc6);
        }
    }
    // overflow: mean excess ~tens of edges for ~half the windows (Poisson tail)
    for (int c = SMAX; ; ++c) {
        long ebw = beg4 + ((long)c * BT_AC + waveBase) * 4;
        if (ebw >= (long)end) break;
        long e0 = beg4 + ((long)c * BT_AC + tid) * 4;
        EW wd; load_win(e0, beg, end, E, ej, qarr, dirs, key8, wd);
        int k[4]; float v[4][6];
#pragma unroll
        for (int u = 0; u < 4; ++u) {
            k[u] = -1;
#pragma unroll
            for (int c2 = 0; c2 < 6; ++c2) v[u][c2] = 0.f;
            if (wd.okv[u]) {
                int li = wd.kv[u] & (NPB - 1);
                float q = wd.qv[u], dx = wd.dxv[u], dy = wd.dyv[u];
                float2 vdj = vd[wd.jv[u]];
                float wq = wendland_dkdq(q);
                float t  = q * wq * INV_H2;
                float s  = -2.f * vdj.x * t;
                float w2 = wq * INV_H3;
                float gwx = dx * w2, gwy = dy * w2;
                float rx = -dx * q * H, ry = -dy * q * H;
                float rji2 = rx * rx + ry * ry + EPS_REF;
                float gT = -t / rji2;
                float gv = gT * vdj.x;
                float rho_ba = REST_RHO * (vdj.y - vdl[li].y);
                k[u] = li;
                v[u][0] = s * dx * dx; v[u][1] = s * dx * dy; v[u][2] = s * dy * dy;
                v[u][3] = rho_ba * gv; v[u][4] = rx * gv;    v[u][5] = ry * gv;
                cst[e0 + u] = __floats2half2_rn(0.5f * rx * gv, 0.5f * ry * gv);
            }
        }
        seg_reduce4<6>(k, v, acc6);
    }
    __syncthreads();

    // ---- pinv (one lane per node), JAX cutoff semantics ----
    if (tid < NPB) {
        float a = acc6[6*tid], b = acc6[6*tid+1], cc = acc6[6*tid+2];
        float half_tr   = 0.5f * (a + cc);
        float half_diff = 0.5f * (a - cc);
        float disc = sqrtf(half_diff * half_diff + b * b);
        float l1 = half_tr + disc, l2 = half_tr - disc;
        float smax = fmaxf(fabsf(l1), fabsf(l2));
        float cutoff = 2.3841858e-6f * smax;   // rcond = 10*max(2,2)*eps_f32
        float i00 = 0.f, i01 = 0.f, i11 = 0.f;
        if (fabsf(l2) > cutoff) {
            float inv = 1.0f / (a * cc - b * b);
            i00 =  cc * inv; i01 = -b * inv; i11 = a * inv;
        } else if (fabsf(l1) > cutoff) {
            float vax = b,       vay = l1 - a;
            float vbx = l1 - cc, vby = b;
            float na = vax*vax + vay*vay, nb = vbx*vbx + vby*vby;
            float vx, vy, n2;
            if (nb >= na) { vx = vbx; vy = vby; n2 = nb; }
            else          { vx = vax; vy = vay; n2 = na; }
            float inv = 1.0f / (l1 * n2);
            i00 = vx*vx*inv; i01 = vx*vy*inv; i11 = vy*vy*inv;
        }
        Lild[3*tid] = i00; Lild[3*tid+1] = i01; Lild[3*tid+2] = i11;
    }
    __syncthreads();

    // ---- phase C: gradRho from stash ----
#pragma unroll
    for (int c = 0; c < SMAX; ++c) {
        long ebw = beg4 + ((long)c * BT_AC + waveBase) * 4;
        if (ebw < (long)end) {
            int k[4]; float v[4][2];
#pragma unroll
            for (int u = 0; u < 4; ++u) {
                int li = li_s[c*4+u];
                k[u] = li; v[u][0] = v[u][1] = 0.f;
                if (li >= 0) {
                    float gwx = gwx_s[c*4+u], gwy = gwy_s[c*4+u];
                    float L0 = Lild[3*li], L1 = Lild[3*li+1], L2v = Lild[3*li+2];
                    float gx = L0 * gwx + L1 * gwy;
                    float gy = L1 * gwx + L2v * gwy;
                    float dm = fabsf(gwx) + fabsf(gwy);
                    float nm = fabsf(gx) + fabsf(gy);
                    float change = fabsf(nm - dm) / (dm + 1e-4f * H);
                    if (!(change < 0.1f)) { gx = gwx; gy = gwy; }   // NaN -> fallback
                    v[u][0] = val_s[c*4+u] * gx;
                    v[u][1] = val_s[c*4+u] * gy;
                }
            }
            seg_reduce4<2>(k, v, gld);
        }
    }
    for (int c = SMAX; ; ++c) {   // overflow recompute (small tail)
        long ebw = beg4 + ((long)c * BT_AC + waveBase) * 4;
        if (ebw >= (long)end) break;
        long e0 = beg4 + ((long)c * BT_AC + tid) * 4;
        EW wd; load_win(e0, beg, end, E, ej, qarr, dirs, key8, wd);
        int k[4]; float v[4][2];
#pragma unroll
        for (int u = 0; u < 4; ++u) {
            k[u] = -1; v[u][0] = v[u][1] = 0.f;
            if (wd.okv[u]) {
                int li = wd.kv[u] & (NPB - 1);
                float q = wd.qv[u], dx = wd.dxv[u], dy = wd.dyv[u];
                float2 vdj = vd[wd.jv[u]];
                float w2 = wendland_dkdq(q) * INV_H3;
                float gwx = dx * w2, gwy = dy * w2;
                float L0 = Lild[3*li], L1 = Lild[3*li+1], L2v = Lild[3*li+2];
                float gx = L0 * gwx + L1 * gwy;
                float gy = L1 * gwx + L2v * gwy;
                float dm = fabsf(gwx) + fabsf(gwy);
                float nm = fabsf(gx) + fabsf(gy);
                float change = fabsf(nm - dm) / (dm + 1e-4f * H);
                if (!(change < 0.1f)) { gx = gwx; gy = gwy; }
                float val = 2.f * REST_RHO * (vdj.y - vdl[li].y) * vdj.x;
                k[u] = li; v[u][0] = val * gx; v[u][1] = val * gy;
            }
        }
        seg_reduce4<2>(k, v, gld);
    }
    __syncthreads();
    if (tid < NPB && n0 + tid < N) {
        float gx = gld[2*tid], gy = gld[2*tid+1];
        g2[n0 + tid]   = make_float2(gx, gy);
        outp[n0 + tid] = acc6[6*tid+3] + 0.5f * (gx * acc6[6*tid+4] + gy * acc6[6*tid+5]);
    }
}

// Pass D (term 3 only): out = K_OUT * (outp + sum_e <g[j], c_e>).
// R11 body unchanged (NPBD=128, BT_D=256, direct 7-bit keys).
__global__ __launch_bounds__(BT_D, 4)
void k_D(const int* __restrict__ ej, const unsigned char* __restrict__ key8,
         const __half2* __restrict__ cst,
         const float2* __restrict__ g2, const float* __restrict__ outp,
         const int* __restrict__ rowptr, float* __restrict__ out, int N, int E) {
    __shared__ float outl[NPBD];
    const int tid = threadIdx.x;
    const int n0  = blockIdx.x * NPBD;
    const int nHi = min(n0 + NPBD, N);
    if (tid < NPBD) outl[tid] = 0.f;
    __syncthreads();
    const int  beg = rowptr[n0], end = rowptr[nHi];
    const long beg4 = (long)beg & ~3L;
    const int  waveBase = tid & ~(WAVE - 1);

    for (int c = 0; ; ++c) {
        long ebw = beg4 + ((long)c * BT_D + waveBase) * 4;
        if (ebw >= (long)end) break;
        long e0 = beg4 + ((long)c * BT_D + tid) * 4;
        int jv[4], kv[4]; float cv[4]; bool okv[4];
        if (e0 + 3 < (long)E) {
            int4   j4 = *(const int4*)(ej + e0);
            float4 c4 = ((const float4*)cst)[e0 >> 2];
            uchar4 kk = *(const uchar4*)(key8 + e0);
            jv[0]=j4.x; jv[1]=j4.y; jv[2]=j4.z; jv[3]=j4.w;
            cv[0]=c4.x; cv[1]=c4.y; cv[2]=c4.z; cv[3]=c4.w;
            kv[0]=kk.x; kv[1]=kk.y; kv[2]=kk.z; kv[3]=kk.w;
        } else {
#pragma unroll
            for (int u = 0; u < 4; ++u) {
                long e = e0 + u;
                if (e < (long)E) { jv[u] = ej[e]; cv[u] = h2_as_f(cst[e]); kv[u] = key8[e]; }
                else             { jv[u] = 0;     cv[u] = 0.f;             kv[u] = 0; }
            }
        }
#pragma unroll
        for (int u = 0; u < 4; ++u) {
            long e = e0 + u;
            okv[u] = (e >= (long)beg) && (e < (long)end);
        }
        // all 4 gathers issued before use (R1-proven)
        float2 gj4[4];
#pragma unroll
        for (int u = 0; u < 4; ++u)
            gj4[u] = okv[u] ? g2[jv[u]] : make_float2(0.f, 0.f);
        int k[4]; float v[4][1];
#pragma unroll
        for (int u = 0; u < 4; ++u) {
            k[u] = -1; v[u][0] = 0.f;
            if (okv[u]) {
                __half2 ch = f_as_h2(cv[u]);
                k[u] = kv[u];                          // direct 7-bit key
                v[u][0] = gj4[u].x * __low2float(ch) + gj4[u].y * __high2float(ch);
            }
        }
        seg_reduce4<1>(k, v, outl);
    }
    __syncthreads();
    if (tid < NPBD && n0 + tid < N)
        out[n0 + tid] = K_OUT * (outp[n0 + tid] + outl[tid]);
}

extern "C" void kernel_launch(void* const* d_in, const int* in_sizes, int n_in,
                              void* d_out, int out_size, void* d_ws, size_t ws_size,
                              hipStream_t stream) {
    const float*  vol  = (const float*)d_in[1];
    const float*  dens = (const float*)d_in[2];
    const float2* dirs = (const float2*)d_in[3];
    const float*  qarr = (const float*)d_in[4];
    const int*    ei   = (const int*)d_in[5];
    const int*    ej   = (const int*)d_in[6];
    const int N = in_sizes[1];
    const int E = in_sizes[4];

    // ws: rowptr int[N+1] | vd f2[N] | g2 f2[N] | outp f[N] | cst h2[E] | key8 u8[E]
    size_t off = 0;
    auto alloc = [&](size_t bytes) { void* r = (char*)d_ws + off;
                                     off = (off + bytes + 15) & ~(size_t)15; return r; };
    int*           rowptr = (int*)          alloc((size_t)(N + 1) * 4);
    float2*        vd     = (float2*)       alloc((size_t)N * 8);
    float2*        g2     = (float2*)       alloc((size_t)N * 8);
    float*         outp   = (float*)        alloc((size_t)N * 4);
    __half2*       cst    = (__half2*)      alloc((size_t)E * 4);
    unsigned char* key8   = (unsigned char*)alloc((size_t)E);
    float*         out    = (float*)d_out;

    const int tb = 256;
    const int gP = (E / 4 + 1 + tb - 1) / tb;   // 4 edges per thread
    const int gB = (N + NPB - 1) / NPB;
    const int gD = (N + NPBD - 1) / NPBD;

    k_prep<<<gP, tb, 0, stream>>>(ei, vol, dens, rowptr, vd, key8, N, E);
    k_AC  <<<gB, BT_AC, 0, stream>>>(ej, qarr, dirs, vd, rowptr, key8, cst, g2, outp, N, E);
    k_D   <<<gD, BT_D, 0, stream>>>(ej, key8, cst, g2, outp, rowptr, out, N, E);
}

// Round 13
// 234.046 us; speedup vs baseline: 1.6957x; 1.0224x over previous
//
#include <hip/hip_runtime.h>
#include <hip/hip_fp16.h>
#include <math.h>

#define WAVE   64
#define NPB    32          // k_AC nodes per window (key low 5 bits)
#define NPBD   128         // k_D nodes per window (key full 7 bits)
#define BLOCKT 256
#define SMAX   2           // stashed 1024-edge chunks (covers <=2048 edges/window)

// ---- constants from the reference ----
#define KC        2.2281692032865347f   // 7/pi
#define H         0.05f
#define INV_H2    400.0f
#define INV_H3    8000.0f
#define EPS_REF   0.00025f              // h^2 * 0.1
#define K_OUT     0.24261080f           // 2*h*DELTA*C0
#define REST_RHO  1000.0f

__device__ __forceinline__ float wendland_dkdq(float q) {
    float o = 1.f - q;
    return -20.f * q * o * o * o * KC;
}

union H2F { __half2 h; float f; };
__device__ __forceinline__ float   h2_as_f(__half2 h) { H2F u; u.h = h; return u.f; }
__device__ __forceinline__ __half2 f_as_h2(float f)   { H2F u; u.f = f; return u.h; }

// ---------------------------------------------------------------------------
// 4-edge-per-lane segmented reduction via shuffle scan (R0-proven).
// Equal keys contiguous in lane order; key<0 skipped. base may be LDS.
// Scan capped at d<=16 (reach 31 lanes; runs up to ~124 edges OK; degrees
// ~Poisson(32), max ~60 -> 2x margin). Correctness-proven R1/R3/R4/R8/R11/R12.
// ---------------------------------------------------------------------------
template<int NV>
__device__ __forceinline__ void seg_reduce4(const int k[4], float v[4][NV], float* base) {
    const int lane = threadIdx.x & (WAVE - 1);
    const int k0 = k[0], k3 = k[3];
    const bool split = (k0 != k3);
    const int firstLen  = (k[1]==k0) ? ((k[2]==k0) ? ((k[3]==k0)?4:3) : 2) : 1;
    const int lastStart = (k[2]==k3) ? ((k[1]==k3) ? ((k[0]==k3)?0:1) : 2) : 3;

    float vin[NV], vfirst[NV];
#pragma unroll
    for (int c = 0; c < NV; ++c) {
        float s = v[3][c];
        if (lastStart <= 2) s += v[2][c];
        if (lastStart <= 1) s += v[1][c];
        if (lastStart == 0) s += v[0][c];
        vin[c] = s;
        float f = v[0][c];
        if (firstLen >= 2) f += v[1][c];
        if (firstLen >= 3) f += v[2][c];
        if (firstLen >= 4) f += v[3][c];
        vfirst[c] = f;
    }
#pragma unroll
    for (int idx = 1; idx <= 2; ++idx) {
        if (idx >= firstLen && idx < lastStart && k[idx] >= 0) {
#pragma unroll
            for (int c = 0; c < NV; ++c)
                atomicAdd(base + (size_t)k[idx] * NV + c, v[idx][c]);
        }
    }
    float S[NV];
#pragma unroll
    for (int c = 0; c < NV; ++c) S[c] = vin[c];
    const int klast = k3;
#pragma unroll
    for (int d = 1; d <= 16; d <<= 1) {   // 5 steps (bound above)
        int okey = __shfl_up(klast, d, WAVE);
        float ov[NV];
#pragma unroll
        for (int c = 0; c < NV; ++c) ov[c] = __shfl_up(S[c], d, WAVE);
        if (lane >= d && okey == klast) {
#pragma unroll
            for (int c = 0; c < NV; ++c) S[c] += ov[c];
        }
    }
    const int prevk = __shfl_up(klast, 1, WAVE);
    float P[NV];
#pragma unroll
    for (int c = 0; c < NV; ++c) P[c] = __shfl_up(S[c], 1, WAVE);
    if (split && k0 >= 0) {
        const bool carry = (lane > 0 && prevk == k0);
#pragma unroll
        for (int c = 0; c < NV; ++c)
            atomicAdd(base + (size_t)k0 * NV + c, vfirst[c] + (carry ? P[c] : 0.f));
    }
    const int nk0 = __shfl_down(k0, 1, WAVE);
    const bool tail = (lane == WAVE - 1) || (nk0 != klast);
    if (tail && klast >= 0) {
#pragma unroll
        for (int c = 0; c < NV; ++c)
            atomicAdd(base + (size_t)klast * NV + c, S[c]);
    }
}

struct EW { int jv[4]; float qv[4], dxv[4], dyv[4]; int kv[4]; bool okv[4]; };

// loads 4 edges + their precomputed 8-bit window keys (ei & 127)
__device__ __forceinline__ void load_win(long e0, int beg, int end, int E,
        const int* __restrict__ ej, const float* __restrict__ qarr,
        const float2* __restrict__ dirs, const unsigned char* __restrict__ key8,
        EW& w) {
    if (e0 + 3 < (long)E) {
        int4   j4 = *(const int4*)(ej + e0);
        float4 q4 = *(const float4*)(qarr + e0);
        float4 dA = *(const float4*)((const float*)dirs + 2 * e0);
        float4 dB = *(const float4*)((const float*)dirs + 2 * e0 + 4);
        uchar4 kk = *(const uchar4*)(key8 + e0);
        w.jv[0]=j4.x; w.jv[1]=j4.y; w.jv[2]=j4.z; w.jv[3]=j4.w;
        w.qv[0]=q4.x; w.qv[1]=q4.y; w.qv[2]=q4.z; w.qv[3]=q4.w;
        w.dxv[0]=dA.x; w.dyv[0]=dA.y; w.dxv[1]=dA.z; w.dyv[1]=dA.w;
        w.dxv[2]=dB.x; w.dyv[2]=dB.y; w.dxv[3]=dB.z; w.dyv[3]=dB.w;
        w.kv[0]=kk.x; w.kv[1]=kk.y; w.kv[2]=kk.z; w.kv[3]=kk.w;
    } else {
#pragma unroll
        for (int u = 0; u < 4; ++u) {
            long e = e0 + u;
            if (e < (long)E) {
                w.jv[u] = ej[e]; w.qv[u] = qarr[e]; w.kv[u] = key8[e];
                float2 d = dirs[e]; w.dxv[u] = d.x; w.dyv[u] = d.y;
            } else { w.jv[u]=0; w.qv[u]=0.f; w.dxv[u]=0.f; w.dyv[u]=0.f; w.kv[u]=0; }
        }
    }
#pragma unroll
    for (int u = 0; u < 4; ++u) {
        long e = e0 + u;
        w.okv[u] = (e >= (long)beg) && (e < (long)end);
    }
}

// Vectorized prep (R12-proven, ~-10us vs scalar): 4 edges/thread (int4 ei,
// uchar4 key8) + 4 nodes/thread (float4 vol/dens -> 2x float4 vd stores).
// rowptr[t]=first edge with i>=t; key8[e]=ei[e]&127.
__global__ void k_prep(const int* __restrict__ ei, const float* __restrict__ vol,
                       const float* __restrict__ dens, int* __restrict__ rowptr,
                       float2* __restrict__ vd, unsigned char* __restrict__ key8,
                       int N, int E) {
    const long e0 = ((long)blockIdx.x * blockDim.x + threadIdx.x) * 4;
    if (e0 <= (long)E) {
        int prev = (e0 == 0) ? -1 : ei[e0 - 1];
        if (e0 + 3 < (long)E) {
            int4 c4 = *(const int4*)(ei + e0);
            uchar4 kk;
            int cur;
            cur = c4.x; for (int t = prev + 1; t <= cur; ++t) rowptr[t] = (int)e0;
            kk.x = (unsigned char)(cur & (NPBD - 1)); prev = cur;
            cur = c4.y; for (int t = prev + 1; t <= cur; ++t) rowptr[t] = (int)e0 + 1;
            kk.y = (unsigned char)(cur & (NPBD - 1)); prev = cur;
            cur = c4.z; for (int t = prev + 1; t <= cur; ++t) rowptr[t] = (int)e0 + 2;
            kk.z = (unsigned char)(cur & (NPBD - 1)); prev = cur;
            cur = c4.w; for (int t = prev + 1; t <= cur; ++t) rowptr[t] = (int)e0 + 3;
            kk.w = (unsigned char)(cur & (NPBD - 1)); prev = cur;
            *(uchar4*)(key8 + e0) = kk;
        } else {
#pragma unroll 4
            for (int u = 0; u < 4; ++u) {
                long e = e0 + u;
                if (e > (long)E) break;
                int cur = (e == (long)E) ? N : ei[e];
                for (int t = prev + 1; t <= cur; ++t) rowptr[t] = (int)e;
                if (e < (long)E) key8[e] = (unsigned char)(cur & (NPBD - 1));
                prev = cur;
            }
        }
    }
    if (e0 + 3 < (long)N) {
        float4 vv = *(const float4*)(vol + e0);
        float4 dd = *(const float4*)(dens + e0);
        ((float4*)vd)[(e0 >> 1)]     = make_float4(vv.x, dd.x, vv.y, dd.y);
        ((float4*)vd)[(e0 >> 1) + 1] = make_float4(vv.z, dd.z, vv.w, dd.w);
    } else {
        for (long n = e0; n < (long)N && n < e0 + 4; ++n)
            vd[n] = make_float2(vol[n], dens[n]);
    }
}

// Fused A+B+C+term1/2 of D (R11-proven best k_AC: NPB=32, BLOCKT=256, SMAX=2,
// li = key & 31).
__global__ __launch_bounds__(BLOCKT, 4)
void k_AC(const int* __restrict__ ej, const float* __restrict__ qarr,
          const float2* __restrict__ dirs, const float2* __restrict__ vd,
          const int* __restrict__ rowptr, const unsigned char* __restrict__ key8,
          __half2* __restrict__ cst,
          float2* __restrict__ g2, float* __restrict__ outp, int N, int E) {
    __shared__ float  acc6[NPB * 6];     // m00,m01,m11,A,Bx,By
    __shared__ float  Lild[NPB * 3];
    __shared__ float  gld[NPB * 2];
    __shared__ float2 vdl[NPB];
    const int tid = threadIdx.x;
    const int n0  = blockIdx.x * NPB;
    const int nHi = min(n0 + NPB, N);
    if (tid < NPB && n0 + tid < N) vdl[tid] = vd[n0 + tid];
    if (tid < NPB * 6) acc6[tid] = 0.f;
    if (tid < NPB * 2) gld[tid] = 0.f;
    __syncthreads();
    const int  beg = rowptr[n0], end = rowptr[nHi];   // uniform -> scalar loads
    const long beg4 = (long)beg & ~3L;
    const int  waveBase = tid & ~(WAVE - 1);

    int   li_s[4 * SMAX];
    float gwx_s[4 * SMAX], gwy_s[4 * SMAX], val_s[4 * SMAX];
#pragma unroll
    for (int x = 0; x < 4 * SMAX; ++x) { li_s[x] = -1; gwx_s[x]=gwy_s[x]=val_s[x]=0.f; }

    // ---- phase A ----
#pragma unroll
    for (int c = 0; c < SMAX; ++c) {
        long ebw = beg4 + ((long)c * BLOCKT + waveBase) * 4;
        if (ebw < (long)end) {
            long e0 = beg4 + ((long)c * BLOCKT + tid) * 4;
            EW wd; load_win(e0, beg, end, E, ej, qarr, dirs, key8, wd);
            const bool all4 = wd.okv[0] && wd.okv[1] && wd.okv[2] && wd.okv[3];
            float4 cpack;
            int k[4]; float v[4][6];
#pragma unroll
            for (int u = 0; u < 4; ++u) {
                k[u] = -1;
#pragma unroll
                for (int c2 = 0; c2 < 6; ++c2) v[u][c2] = 0.f;
                if (wd.okv[u]) {
                    int li = wd.kv[u] & (NPB - 1);     // low 5 bits of window key
                    float q = wd.qv[u], dx = wd.dxv[u], dy = wd.dyv[u];
                    float2 vdj = vd[wd.jv[u]];
                    float wq = wendland_dkdq(q);
                    float t  = q * wq * INV_H2;        // unit dirs: gw.r_ba = -t
                    float s  = -2.f * vdj.x * t;       // >= 0
                    float w2 = wq * INV_H3;
                    float gwx = dx * w2, gwy = dy * w2;
                    float rx = -dx * q * H, ry = -dy * q * H;
                    float rji2 = rx * rx + ry * ry + EPS_REF;
                    float gT = -t / rji2;
                    float gv = gT * vdj.x;
                    float rho_ba = REST_RHO * (vdj.y - vdl[li].y);
                    k[u] = li;
                    v[u][0] = s * dx * dx; v[u][1] = s * dx * dy; v[u][2] = s * dy * dy;
                    v[u][3] = rho_ba * gv; v[u][4] = rx * gv;    v[u][5] = ry * gv;
                    __half2 cp = __floats2half2_rn(0.5f * rx * gv, 0.5f * ry * gv);
                    if (all4) (&cpack.x)[u] = h2_as_f(cp);
                    else      cst[e0 + u] = cp;
                    li_s[c*4+u] = li; gwx_s[c*4+u] = gwx; gwy_s[c*4+u] = gwy;
                    val_s[c*4+u] = 2.f * rho_ba * vdj.x;
                }
            }
            if (all4) ((float4*)cst)[e0 >> 2] = cpack;
            seg_reduce4<6>(k, v, acc6);
        }
    }
    // overflow (window > SMAX*1024 edges; practically never at avg degree 32)
    for (int c = SMAX; ; ++c) {
        long ebw = beg4 + ((long)c * BLOCKT + waveBase) * 4;
        if (ebw >= (long)end) break;
        long e0 = beg4 + ((long)c * BLOCKT + tid) * 4;
        EW wd; load_win(e0, beg, end, E, ej, qarr, dirs, key8, wd);
        int k[4]; float v[4][6];
#pragma unroll
        for (int u = 0; u < 4; ++u) {
            k[u] = -1;
#pragma unroll
            for (int c2 = 0; c2 < 6; ++c2) v[u][c2] = 0.f;
            if (wd.okv[u]) {
                int li = wd.kv[u] & (NPB - 1);
                float q = wd.qv[u], dx = wd.dxv[u], dy = wd.dyv[u];
                float2 vdj = vd[wd.jv[u]];
                float wq = wendland_dkdq(q);
                float t  = q * wq * INV_H2;
                float s  = -2.f * vdj.x * t;
                float w2 = wq * INV_H3;
                float gwx = dx * w2, gwy = dy * w2;
                float rx = -dx * q * H, ry = -dy * q * H;
                float rji2 = rx * rx + ry * ry + EPS_REF;
                float gT = -t / rji2;
                float gv = gT * vdj.x;
                float rho_ba = REST_RHO * (vdj.y - vdl[li].y);
                k[u] = li;
                v[u][0] = s * dx * dx; v[u][1] = s * dx * dy; v[u][2] = s * dy * dy;
                v[u][3] = rho_ba * gv; v[u][4] = rx * gv;    v[u][5] = ry * gv;
                cst[e0 + u] = __floats2half2_rn(0.5f * rx * gv, 0.5f * ry * gv);
            }
        }
        seg_reduce4<6>(k, v, acc6);
    }
    __syncthreads();

    // ---- pinv (one lane per node), JAX cutoff semantics ----
    if (tid < NPB) {
        float a = acc6[6*tid], b = acc6[6*tid+1], cc = acc6[6*tid+2];
        float half_tr   = 0.5f * (a + cc);
        float half_diff = 0.5f * (a - cc);
        float disc = sqrtf(half_diff * half_diff + b * b);
        float l1 = half_tr + disc, l2 = half_tr - disc;
        float smax = fmaxf(fabsf(l1), fabsf(l2));
        float cutoff = 2.3841858e-6f * smax;   // rcond = 10*max(2,2)*eps_f32
        float i00 = 0.f, i01 = 0.f, i11 = 0.f;
        if (fabsf(l2) > cutoff) {
            float inv = 1.0f / (a * cc - b * b);
            i00 =  cc * inv; i01 = -b * inv; i11 = a * inv;
        } else if (fabsf(l1) > cutoff) {
            float vax = b,       vay = l1 - a;
            float vbx = l1 - cc, vby = b;
            float na = vax*vax + vay*vay, nb = vbx*vbx + vby*vby;
            float vx, vy, n2;
            if (nb >= na) { vx = vbx; vy = vby; n2 = nb; }
            else          { vx = vax; vy = vay; n2 = na; }
            float inv = 1.0f / (l1 * n2);
            i00 = vx*vx*inv; i01 = vx*vy*inv; i11 = vy*vy*inv;
        }
        Lild[3*tid] = i00; Lild[3*tid+1] = i01; Lild[3*tid+2] = i11;
    }
    __syncthreads();

    // ---- phase C: gradRho from stash ----
#pragma unroll
    for (int c = 0; c < SMAX; ++c) {
        long ebw = beg4 + ((long)c * BLOCKT + waveBase) * 4;
        if (ebw < (long)end) {
            int k[4]; float v[4][2];
#pragma unroll
            for (int u = 0; u < 4; ++u) {
                int li = li_s[c*4+u];
                k[u] = li; v[u][0] = v[u][1] = 0.f;
                if (li >= 0) {
                    float gwx = gwx_s[c*4+u], gwy = gwy_s[c*4+u];
                    float L0 = Lild[3*li], L1 = Lild[3*li+1], L2v = Lild[3*li+2];
                    float gx = L0 * gwx + L1 * gwy;
                    float gy = L1 * gwx + L2v * gwy;
                    float dm = fabsf(gwx) + fabsf(gwy);
                    float nm = fabsf(gx) + fabsf(gy);
                    float change = fabsf(nm - dm) / (dm + 1e-4f * H);
                    if (!(change < 0.1f)) { gx = gwx; gy = gwy; }   // NaN -> fallback
                    v[u][0] = val_s[c*4+u] * gx;
                    v[u][1] = val_s[c*4+u] * gy;
                }
            }
            seg_reduce4<2>(k, v, gld);
        }
    }
    for (int c = SMAX; ; ++c) {   // overflow recompute (rare)
        long ebw = beg4 + ((long)c * BLOCKT + waveBase) * 4;
        if (ebw >= (long)end) break;
        long e0 = beg4 + ((long)c * BLOCKT + tid) * 4;
        EW wd; load_win(e0, beg, end, E, ej, qarr, dirs, key8, wd);
        int k[4]; float v[4][2];
#pragma unroll
        for (int u = 0; u < 4; ++u) {
            k[u] = -1; v[u][0] = v[u][1] = 0.f;
            if (wd.okv[u]) {
                int li = wd.kv[u] & (NPB - 1);
                float q = wd.qv[u], dx = wd.dxv[u], dy = wd.dyv[u];
                float2 vdj = vd[wd.jv[u]];
                float w2 = wendland_dkdq(q) * INV_H3;
                float gwx = dx * w2, gwy = dy * w2;
                float L0 = Lild[3*li], L1 = Lild[3*li+1], L2v = Lild[3*li+2];
                float gx = L0 * gwx + L1 * gwy;
                float gy = L1 * gwx + L2v * gwy;
                float dm = fabsf(gwx) + fabsf(gwy);
                float nm = fabsf(gx) + fabsf(gy);
                float change = fabsf(nm - dm) / (dm + 1e-4f * H);
                if (!(change < 0.1f)) { gx = gwx; gy = gwy; }
                float val = 2.f * REST_RHO * (vdj.y - vdl[li].y) * vdj.x;
                k[u] = li; v[u][0] = val * gx; v[u][1] = val * gy;
            }
        }
        seg_reduce4<2>(k, v, gld);
    }
    __syncthreads();
    if (tid < NPB && n0 + tid < N) {
        float gx = gld[2*tid], gy = gld[2*tid+1];
        g2[n0 + tid]   = make_float2(gx, gy);
        outp[n0 + tid] = acc6[6*tid+3] + 0.5f * (gx * acc6[6*tid+4] + gy * acc6[6*tid+5]);
    }
}

// Pass D (term 3 only): out = K_OUT * (outp + sum_e <g[j], c_e>).
// R11 body unchanged (NPBD=128, BLOCKT=256, direct 7-bit keys).
__global__ __launch_bounds__(BLOCKT, 4)
void k_D(const int* __restrict__ ej, const unsigned char* __restrict__ key8,
         const __half2* __restrict__ cst,
         const float2* __restrict__ g2, const float* __restrict__ outp,
         const int* __restrict__ rowptr, float* __restrict__ out, int N, int E) {
    __shared__ float outl[NPBD];
    const int tid = threadIdx.x;
    const int n0  = blockIdx.x * NPBD;
    const int nHi = min(n0 + NPBD, N);
    if (tid < NPBD) outl[tid] = 0.f;
    __syncthreads();
    const int  beg = rowptr[n0], end = rowptr[nHi];
    const long beg4 = (long)beg & ~3L;
    const int  waveBase = tid & ~(WAVE - 1);

    for (int c = 0; ; ++c) {
        long ebw = beg4 + ((long)c * BLOCKT + waveBase) * 4;
        if (ebw >= (long)end) break;
        long e0 = beg4 + ((long)c * BLOCKT + tid) * 4;
        int jv[4], kv[4]; float cv[4]; bool okv[4];
        if (e0 + 3 < (long)E) {
            int4   j4 = *(const int4*)(ej + e0);
            float4 c4 = ((const float4*)cst)[e0 >> 2];
            uchar4 kk = *(const uchar4*)(key8 + e0);
            jv[0]=j4.x; jv[1]=j4.y; jv[2]=j4.z; jv[3]=j4.w;
            cv[0]=c4.x; cv[1]=c4.y; cv[2]=c4.z; cv[3]=c4.w;
            kv[0]=kk.x; kv[1]=kk.y; kv[2]=kk.z; kv[3]=kk.w;
        } else {
#pragma unroll
            for (int u = 0; u < 4; ++u) {
                long e = e0 + u;
                if (e < (long)E) { jv[u] = ej[e]; cv[u] = h2_as_f(cst[e]); kv[u] = key8[e]; }
                else             { jv[u] = 0;     cv[u] = 0.f;             kv[u] = 0; }
            }
        }
#pragma unroll
        for (int u = 0; u < 4; ++u) {
            long e = e0 + u;
            okv[u] = (e >= (long)beg) && (e < (long)end);
        }
        // all 4 gathers issued before use (R1-proven)
        float2 gj4[4];
#pragma unroll
        for (int u = 0; u < 4; ++u)
            gj4[u] = okv[u] ? g2[jv[u]] : make_float2(0.f, 0.f);
        int k[4]; float v[4][1];
#pragma unroll
        for (int u = 0; u < 4; ++u) {
            k[u] = -1; v[u][0] = 0.f;
            if (okv[u]) {
                __half2 ch = f_as_h2(cv[u]);
                k[u] = kv[u];                          // direct 7-bit key
                v[u][0] = gj4[u].x * __low2float(ch) + gj4[u].y * __high2float(ch);
            }
        }
        seg_reduce4<1>(k, v, outl);
    }
    __syncthreads();
    if (tid < NPBD && n0 + tid < N)
        out[n0 + tid] = K_OUT * (outp[n0 + tid] + outl[tid]);
}

extern "C" void kernel_launch(void* const* d_in, const int* in_sizes, int n_in,
                              void* d_out, int out_size, void* d_ws, size_t ws_size,
                              hipStream_t stream) {
    const float*  vol  = (const float*)d_in[1];
    const float*  dens = (const float*)d_in[2];
    const float2* dirs = (const float2*)d_in[3];
    const float*  qarr = (const float*)d_in[4];
    const int*    ei   = (const int*)d_in[5];
    const int*    ej   = (const int*)d_in[6];
    const int N = in_sizes[1];
    const int E = in_sizes[4];

    // ws: rowptr int[N+1] | vd f2[N] | g2 f2[N] | outp f[N] | cst h2[E] | key8 u8[E]
    size_t off = 0;
    auto alloc = [&](size_t bytes) { void* r = (char*)d_ws + off;
                                     off = (off + bytes + 15) & ~(size_t)15; return r; };
    int*           rowptr = (int*)          alloc((size_t)(N + 1) * 4);
    float2*        vd     = (float2*)       alloc((size_t)N * 8);
    float2*        g2     = (float2*)       alloc((size_t)N * 8);
    float*         outp   = (float*)        alloc((size_t)N * 4);
    __half2*       cst    = (__half2*)      alloc((size_t)E * 4);
    unsigned char* key8   = (unsigned char*)alloc((size_t)E);
    float*         out    = (float*)d_out;

    const int tb = 256;
    const int gP = (E / 4 + 1 + tb - 1) / tb;   // 4 edges per thread
    const int gB = (N + NPB - 1) / NPB;
    const int gD = (N + NPBD - 1) / NPBD;

    k_prep<<<gP, tb, 0, stream>>>(ei, vol, dens, rowptr, vd, key8, N, E);
    k_AC  <<<gB, BLOCKT, 0, stream>>>(ej, qarr, dirs, vd, rowptr, key8, cst, g2, outp, N, E);
    k_D   <<<gD, BLOCKT, 0, stream>>>(ej, key8, cst, g2, outp, rowptr, out, N, E);
}

// Round 14
// 233.520 us; speedup vs baseline: 1.6995x; 1.0023x over previous
//
#include <hip/hip_runtime.h>
#include <hip/hip_fp16.h>
#include <math.h>

#define WAVE   64
#define NPB    32          // k_AC nodes per window (key low 5 bits)
#define NPBD   128         // k_D nodes per window (key full 7 bits)
#define BLOCKT 256
#define SMAX   2           // stashed 1024-edge chunks (covers <=2048 edges/window)

// ---- constants from the reference ----
#define KC        2.2281692032865347f   // 7/pi
#define H         0.05f
#define INV_H2    400.0f
#define INV_H3    8000.0f
#define EPS_REF   0.00025f              // h^2 * 0.1
#define K_OUT     0.24261080f           // 2*h*DELTA*C0
#define REST_RHO  1000.0f

__device__ __forceinline__ float wendland_dkdq(float q) {
    float o = 1.f - q;
    return -20.f * q * o * o * o * KC;
}

union H2F { __half2 h; float f; };
__device__ __forceinline__ float   h2_as_f(__half2 h) { H2F u; u.h = h; return u.f; }
__device__ __forceinline__ __half2 f_as_h2(float f)   { H2F u; u.f = f; return u.h; }

// ---------------------------------------------------------------------------
// 4-edge-per-lane segmented reduction via shuffle scan (R0-proven).
// Equal keys contiguous in lane order; key<0 skipped. base may be LDS.
// Scan capped at d<=16 (reach 31 lanes; runs up to ~124 edges OK; degrees
// ~Poisson(32), max ~60 -> 2x margin). Correctness-proven R1..R13.
// ---------------------------------------------------------------------------
template<int NV>
__device__ __forceinline__ void seg_reduce4(const int k[4], float v[4][NV], float* base) {
    const int lane = threadIdx.x & (WAVE - 1);
    const int k0 = k[0], k3 = k[3];
    const bool split = (k0 != k3);
    const int firstLen  = (k[1]==k0) ? ((k[2]==k0) ? ((k[3]==k0)?4:3) : 2) : 1;
    const int lastStart = (k[2]==k3) ? ((k[1]==k3) ? ((k[0]==k3)?0:1) : 2) : 3;

    float vin[NV], vfirst[NV];
#pragma unroll
    for (int c = 0; c < NV; ++c) {
        float s = v[3][c];
        if (lastStart <= 2) s += v[2][c];
        if (lastStart <= 1) s += v[1][c];
        if (lastStart == 0) s += v[0][c];
        vin[c] = s;
        float f = v[0][c];
        if (firstLen >= 2) f += v[1][c];
        if (firstLen >= 3) f += v[2][c];
        if (firstLen >= 4) f += v[3][c];
        vfirst[c] = f;
    }
#pragma unroll
    for (int idx = 1; idx <= 2; ++idx) {
        if (idx >= firstLen && idx < lastStart && k[idx] >= 0) {
#pragma unroll
            for (int c = 0; c < NV; ++c)
                atomicAdd(base + (size_t)k[idx] * NV + c, v[idx][c]);
        }
    }
    float S[NV];
#pragma unroll
    for (int c = 0; c < NV; ++c) S[c] = vin[c];
    const int klast = k3;
#pragma unroll
    for (int d = 1; d <= 16; d <<= 1) {   // 5 steps (bound above)
        int okey = __shfl_up(klast, d, WAVE);
        float ov[NV];
#pragma unroll
        for (int c = 0; c < NV; ++c) ov[c] = __shfl_up(S[c], d, WAVE);
        if (lane >= d && okey == klast) {
#pragma unroll
            for (int c = 0; c < NV; ++c) S[c] += ov[c];
        }
    }
    const int prevk = __shfl_up(klast, 1, WAVE);
    float P[NV];
#pragma unroll
    for (int c = 0; c < NV; ++c) P[c] = __shfl_up(S[c], 1, WAVE);
    if (split && k0 >= 0) {
        const bool carry = (lane > 0 && prevk == k0);
#pragma unroll
        for (int c = 0; c < NV; ++c)
            atomicAdd(base + (size_t)k0 * NV + c, vfirst[c] + (carry ? P[c] : 0.f));
    }
    const int nk0 = __shfl_down(k0, 1, WAVE);
    const bool tail = (lane == WAVE - 1) || (nk0 != klast);
    if (tail && klast >= 0) {
#pragma unroll
        for (int c = 0; c < NV; ++c)
            atomicAdd(base + (size_t)klast * NV + c, S[c]);
    }
}

struct EW { int jv[4]; float qv[4], dxv[4], dyv[4]; int kv[4]; bool okv[4]; };

// loads 4 edges + their precomputed 8-bit window keys (ei & 127)
__device__ __forceinline__ void load_win(long e0, int beg, int end, int E,
        const int* __restrict__ ej, const float* __restrict__ qarr,
        const float2* __restrict__ dirs, const unsigned char* __restrict__ key8,
        EW& w) {
    if (e0 + 3 < (long)E) {
        int4   j4 = *(const int4*)(ej + e0);
        float4 q4 = *(const float4*)(qarr + e0);
        float4 dA = *(const float4*)((const float*)dirs + 2 * e0);
        float4 dB = *(const float4*)((const float*)dirs + 2 * e0 + 4);
        uchar4 kk = *(const uchar4*)(key8 + e0);
        w.jv[0]=j4.x; w.jv[1]=j4.y; w.jv[2]=j4.z; w.jv[3]=j4.w;
        w.qv[0]=q4.x; w.qv[1]=q4.y; w.qv[2]=q4.z; w.qv[3]=q4.w;
        w.dxv[0]=dA.x; w.dyv[0]=dA.y; w.dxv[1]=dA.z; w.dyv[1]=dA.w;
        w.dxv[2]=dB.x; w.dyv[2]=dB.y; w.dxv[3]=dB.z; w.dyv[3]=dB.w;
        w.kv[0]=kk.x; w.kv[1]=kk.y; w.kv[2]=kk.z; w.kv[3]=kk.w;
    } else {
#pragma unroll
        for (int u = 0; u < 4; ++u) {
            long e = e0 + u;
            if (e < (long)E) {
                w.jv[u] = ej[e]; w.qv[u] = qarr[e]; w.kv[u] = key8[e];
                float2 d = dirs[e]; w.dxv[u] = d.x; w.dyv[u] = d.y;
            } else { w.jv[u]=0; w.qv[u]=0.f; w.dxv[u]=0.f; w.dyv[u]=0.f; w.kv[u]=0; }
        }
    }
#pragma unroll
    for (int u = 0; u < 4; ++u) {
        long e = e0 + u;
        w.okv[u] = (e >= (long)beg) && (e < (long)end);
    }
}

// Vectorized prep (R12-proven, ~-10us vs scalar): 4 edges/thread (int4 ei,
// uchar4 key8) + 4 nodes/thread (float4 vol/dens -> 2x float4 vd stores).
// rowptr[t]=first edge with i>=t; key8[e]=ei[e]&127.
__global__ void k_prep(const int* __restrict__ ei, const float* __restrict__ vol,
                       const float* __restrict__ dens, int* __restrict__ rowptr,
                       float2* __restrict__ vd, unsigned char* __restrict__ key8,
                       int N, int E) {
    const long e0 = ((long)blockIdx.x * blockDim.x + threadIdx.x) * 4;
    if (e0 <= (long)E) {
        int prev = (e0 == 0) ? -1 : ei[e0 - 1];
        if (e0 + 3 < (long)E) {
            int4 c4 = *(const int4*)(ei + e0);
            uchar4 kk;
            int cur;
            cur = c4.x; for (int t = prev + 1; t <= cur; ++t) rowptr[t] = (int)e0;
            kk.x = (unsigned char)(cur & (NPBD - 1)); prev = cur;
            cur = c4.y; for (int t = prev + 1; t <= cur; ++t) rowptr[t] = (int)e0 + 1;
            kk.y = (unsigned char)(cur & (NPBD - 1)); prev = cur;
            cur = c4.z; for (int t = prev + 1; t <= cur; ++t) rowptr[t] = (int)e0 + 2;
            kk.z = (unsigned char)(cur & (NPBD - 1)); prev = cur;
            cur = c4.w; for (int t = prev + 1; t <= cur; ++t) rowptr[t] = (int)e0 + 3;
            kk.w = (unsigned char)(cur & (NPBD - 1)); prev = cur;
            *(uchar4*)(key8 + e0) = kk;
        } else {
#pragma unroll 4
            for (int u = 0; u < 4; ++u) {
                long e = e0 + u;
                if (e > (long)E) break;
                int cur = (e == (long)E) ? N : ei[e];
                for (int t = prev + 1; t <= cur; ++t) rowptr[t] = (int)e;
                if (e < (long)E) key8[e] = (unsigned char)(cur & (NPBD - 1));
                prev = cur;
            }
        }
    }
    if (e0 + 3 < (long)N) {
        float4 vv = *(const float4*)(vol + e0);
        float4 dd = *(const float4*)(dens + e0);
        ((float4*)vd)[(e0 >> 1)]     = make_float4(vv.x, dd.x, vv.y, dd.y);
        ((float4*)vd)[(e0 >> 1) + 1] = make_float4(vv.z, dd.z, vv.w, dd.w);
    } else {
        for (long n = e0; n < (long)N && n < e0 + 4; ++n)
            vd[n] = make_float2(vol[n], dens[n]);
    }
}

// Fused A+B+C+term1/2 of D (R11/R13-proven best k_AC: NPB=32, BLOCKT=256,
// SMAX=2, li = key & 31). UNCHANGED from R13.
__global__ __launch_bounds__(BLOCKT, 4)
void k_AC(const int* __restrict__ ej, const float* __restrict__ qarr,
          const float2* __restrict__ dirs, const float2* __restrict__ vd,
          const int* __restrict__ rowptr, const unsigned char* __restrict__ key8,
          __half2* __restrict__ cst,
          float2* __restrict__ g2, float* __restrict__ outp, int N, int E) {
    __shared__ float  acc6[NPB * 6];     // m00,m01,m11,A,Bx,By
    __shared__ float  Lild[NPB * 3];
    __shared__ float  gld[NPB * 2];
    __shared__ float2 vdl[NPB];
    const int tid = threadIdx.x;
    const int n0  = blockIdx.x * NPB;
    const int nHi = min(n0 + NPB, N);
    if (tid < NPB && n0 + tid < N) vdl[tid] = vd[n0 + tid];
    if (tid < NPB * 6) acc6[tid] = 0.f;
    if (tid < NPB * 2) gld[tid] = 0.f;
    __syncthreads();
    const int  beg = rowptr[n0], end = rowptr[nHi];   // uniform -> scalar loads
    const long beg4 = (long)beg & ~3L;
    const int  waveBase = tid & ~(WAVE - 1);

    int   li_s[4 * SMAX];
    float gwx_s[4 * SMAX], gwy_s[4 * SMAX], val_s[4 * SMAX];
#pragma unroll
    for (int x = 0; x < 4 * SMAX; ++x) { li_s[x] = -1; gwx_s[x]=gwy_s[x]=val_s[x]=0.f; }

    // ---- phase A ----
#pragma unroll
    for (int c = 0; c < SMAX; ++c) {
        long ebw = beg4 + ((long)c * BLOCKT + waveBase) * 4;
        if (ebw < (long)end) {
            long e0 = beg4 + ((long)c * BLOCKT + tid) * 4;
            EW wd; load_win(e0, beg, end, E, ej, qarr, dirs, key8, wd);
            const bool all4 = wd.okv[0] && wd.okv[1] && wd.okv[2] && wd.okv[3];
            float4 cpack;
            int k[4]; float v[4][6];
#pragma unroll
            for (int u = 0; u < 4; ++u) {
                k[u] = -1;
#pragma unroll
                for (int c2 = 0; c2 < 6; ++c2) v[u][c2] = 0.f;
                if (wd.okv[u]) {
                    int li = wd.kv[u] & (NPB - 1);     // low 5 bits of window key
                    float q = wd.qv[u], dx = wd.dxv[u], dy = wd.dyv[u];
                    float2 vdj = vd[wd.jv[u]];
                    float wq = wendland_dkdq(q);
                    float t  = q * wq * INV_H2;        // unit dirs: gw.r_ba = -t
                    float s  = -2.f * vdj.x * t;       // >= 0
                    float w2 = wq * INV_H3;
                    float gwx = dx * w2, gwy = dy * w2;
                    float rx = -dx * q * H, ry = -dy * q * H;
                    float rji2 = rx * rx + ry * ry + EPS_REF;
                    float gT = -t / rji2;
                    float gv = gT * vdj.x;
                    float rho_ba = REST_RHO * (vdj.y - vdl[li].y);
                    k[u] = li;
                    v[u][0] = s * dx * dx; v[u][1] = s * dx * dy; v[u][2] = s * dy * dy;
                    v[u][3] = rho_ba * gv; v[u][4] = rx * gv;    v[u][5] = ry * gv;
                    __half2 cp = __floats2half2_rn(0.5f * rx * gv, 0.5f * ry * gv);
                    if (all4) (&cpack.x)[u] = h2_as_f(cp);
                    else      cst[e0 + u] = cp;
                    li_s[c*4+u] = li; gwx_s[c*4+u] = gwx; gwy_s[c*4+u] = gwy;
                    val_s[c*4+u] = 2.f * rho_ba * vdj.x;
                }
            }
            if (all4) ((float4*)cst)[e0 >> 2] = cpack;
            seg_reduce4<6>(k, v, acc6);
        }
    }
    // overflow (window > SMAX*1024 edges; practically never at avg degree 32)
    for (int c = SMAX; ; ++c) {
        long ebw = beg4 + ((long)c * BLOCKT + waveBase) * 4;
        if (ebw >= (long)end) break;
        long e0 = beg4 + ((long)c * BLOCKT + tid) * 4;
        EW wd; load_win(e0, beg, end, E, ej, qarr, dirs, key8, wd);
        int k[4]; float v[4][6];
#pragma unroll
        for (int u = 0; u < 4; ++u) {
            k[u] = -1;
#pragma unroll
            for (int c2 = 0; c2 < 6; ++c2) v[u][c2] = 0.f;
            if (wd.okv[u]) {
                int li = wd.kv[u] & (NPB - 1);
                float q = wd.qv[u], dx = wd.dxv[u], dy = wd.dyv[u];
                float2 vdj = vd[wd.jv[u]];
                float wq = wendland_dkdq(q);
                float t  = q * wq * INV_H2;
                float s  = -2.f * vdj.x * t;
                float w2 = wq * INV_H3;
                float gwx = dx * w2, gwy = dy * w2;
                float rx = -dx * q * H, ry = -dy * q * H;
                float rji2 = rx * rx + ry * ry + EPS_REF;
                float gT = -t / rji2;
                float gv = gT * vdj.x;
                float rho_ba = REST_RHO * (vdj.y - vdl[li].y);
                k[u] = li;
                v[u][0] = s * dx * dx; v[u][1] = s * dx * dy; v[u][2] = s * dy * dy;
                v[u][3] = rho_ba * gv; v[u][4] = rx * gv;    v[u][5] = ry * gv;
                cst[e0 + u] = __floats2half2_rn(0.5f * rx * gv, 0.5f * ry * gv);
            }
        }
        seg_reduce4<6>(k, v, acc6);
    }
    __syncthreads();

    // ---- pinv (one lane per node), JAX cutoff semantics ----
    if (tid < NPB) {
        float a = acc6[6*tid], b = acc6[6*tid+1], cc = acc6[6*tid+2];
        float half_tr   = 0.5f * (a + cc);
        float half_diff = 0.5f * (a - cc);
        float disc = sqrtf(half_diff * half_diff + b * b);
        float l1 = half_tr + disc, l2 = half_tr - disc;
        float smax = fmaxf(fabsf(l1), fabsf(l2));
        float cutoff = 2.3841858e-6f * smax;   // rcond = 10*max(2,2)*eps_f32
        float i00 = 0.f, i01 = 0.f, i11 = 0.f;
        if (fabsf(l2) > cutoff) {
            float inv = 1.0f / (a * cc - b * b);
            i00 =  cc * inv; i01 = -b * inv; i11 = a * inv;
        } else if (fabsf(l1) > cutoff) {
            float vax = b,       vay = l1 - a;
            float vbx = l1 - cc, vby = b;
            float na = vax*vax + vay*vay, nb = vbx*vbx + vby*vby;
            float vx, vy, n2;
            if (nb >= na) { vx = vbx; vy = vby; n2 = nb; }
            else          { vx = vax; vy = vay; n2 = na; }
            float inv = 1.0f / (l1 * n2);
            i00 = vx*vx*inv; i01 = vx*vy*inv; i11 = vy*vy*inv;
        }
        Lild[3*tid] = i00; Lild[3*tid+1] = i01; Lild[3*tid+2] = i11;
    }
    __syncthreads();

    // ---- phase C: gradRho from stash ----
#pragma unroll
    for (int c = 0; c < SMAX; ++c) {
        long ebw = beg4 + ((long)c * BLOCKT + waveBase) * 4;
        if (ebw < (long)end) {
            int k[4]; float v[4][2];
#pragma unroll
            for (int u = 0; u < 4; ++u) {
                int li = li_s[c*4+u];
                k[u] = li; v[u][0] = v[u][1] = 0.f;
                if (li >= 0) {
                    float gwx = gwx_s[c*4+u], gwy = gwy_s[c*4+u];
                    float L0 = Lild[3*li], L1 = Lild[3*li+1], L2v = Lild[3*li+2];
                    float gx = L0 * gwx + L1 * gwy;
                    float gy = L1 * gwx + L2v * gwy;
                    float dm = fabsf(gwx) + fabsf(gwy);
                    float nm = fabsf(gx) + fabsf(gy);
                    float change = fabsf(nm - dm) / (dm + 1e-4f * H);
                    if (!(change < 0.1f)) { gx = gwx; gy = gwy; }   // NaN -> fallback
                    v[u][0] = val_s[c*4+u] * gx;
                    v[u][1] = val_s[c*4+u] * gy;
                }
            }
            seg_reduce4<2>(k, v, gld);
        }
    }
    for (int c = SMAX; ; ++c) {   // overflow recompute (rare)
        long ebw = beg4 + ((long)c * BLOCKT + waveBase) * 4;
        if (ebw >= (long)end) break;
        long e0 = beg4 + ((long)c * BLOCKT + tid) * 4;
        EW wd; load_win(e0, beg, end, E, ej, qarr, dirs, key8, wd);
        int k[4]; float v[4][2];
#pragma unroll
        for (int u = 0; u < 4; ++u) {
            k[u] = -1; v[u][0] = v[u][1] = 0.f;
            if (wd.okv[u]) {
                int li = wd.kv[u] & (NPB - 1);
                float q = wd.qv[u], dx = wd.dxv[u], dy = wd.dyv[u];
                float2 vdj = vd[wd.jv[u]];
                float w2 = wendland_dkdq(q) * INV_H3;
                float gwx = dx * w2, gwy = dy * w2;
                float L0 = Lild[3*li], L1 = Lild[3*li+1], L2v = Lild[3*li+2];
                float gx = L0 * gwx + L1 * gwy;
                float gy = L1 * gwx + L2v * gwy;
                float dm = fabsf(gwx) + fabsf(gwy);
                float nm = fabsf(gx) + fabsf(gy);
                float change = fabsf(nm - dm) / (dm + 1e-4f * H);
                if (!(change < 0.1f)) { gx = gwx; gy = gwy; }
                float val = 2.f * REST_RHO * (vdj.y - vdl[li].y) * vdj.x;
                k[u] = li; v[u][0] = val * gx; v[u][1] = val * gy;
            }
        }
        seg_reduce4<2>(k, v, gld);
    }
    __syncthreads();
    if (tid < NPB && n0 + tid < N) {
        float gx = gld[2*tid], gy = gld[2*tid+1];
        g2[n0 + tid]   = make_float2(gx, gy);
        outp[n0 + tid] = acc6[6*tid+3] + 0.5f * (gx * acc6[6*tid+4] + gy * acc6[6*tid+5]);
    }
}

// raw per-chunk register buffer for k_D's pipelined loop
struct DW { int jv[4]; float cv[4]; int kv[4]; };

__device__ __forceinline__ void load_dw(long e0, int E,
        const int* __restrict__ ej, const __half2* __restrict__ cst,
        const unsigned char* __restrict__ key8, DW& d) {
    if (e0 + 3 < (long)E) {
        int4   j4 = *(const int4*)(ej + e0);
        float4 c4 = ((const float4*)cst)[e0 >> 2];
        uchar4 kk = *(const uchar4*)(key8 + e0);
        d.jv[0]=j4.x; d.jv[1]=j4.y; d.jv[2]=j4.z; d.jv[3]=j4.w;
        d.cv[0]=c4.x; d.cv[1]=c4.y; d.cv[2]=c4.z; d.cv[3]=c4.w;
        d.kv[0]=kk.x; d.kv[1]=kk.y; d.kv[2]=kk.z; d.kv[3]=kk.w;
    } else {
#pragma unroll
        for (int u = 0; u < 4; ++u) {
            long e = e0 + u;
            if (e < (long)E) { d.jv[u] = ej[e]; d.cv[u] = h2_as_f(cst[e]); d.kv[u] = key8[e]; }
            else             { d.jv[u] = 0;     d.cv[u] = 0.f;             d.kv[u] = 0; }
        }
    }
}

// Pass D (term 3 only): out = K_OUT * (outp + sum_e <g[j], c_e>).
// R13 body + software-pipelined chunk loop: next chunk's stream loads and
// current chunk's gathers are issued before the current scan -> HBM/L2
// latency hides under compute. NPBD=128, direct 7-bit keys.
__global__ __launch_bounds__(BLOCKT, 4)
void k_D(const int* __restrict__ ej, const unsigned char* __restrict__ key8,
         const __half2* __restrict__ cst,
         const float2* __restrict__ g2, const float* __restrict__ outp,
         const int* __restrict__ rowptr, float* __restrict__ out, int N, int E) {
    __shared__ float outl[NPBD];
    const int tid = threadIdx.x;
    const int n0  = blockIdx.x * NPBD;
    const int nHi = min(n0 + NPBD, N);
    if (tid < NPBD) outl[tid] = 0.f;
    __syncthreads();
    const int  beg = rowptr[n0], end = rowptr[nHi];
    const long beg4 = (long)beg & ~3L;
    const int  waveBase = tid & ~(WAVE - 1);

    // prologue: chunk 0
    long ebw0 = beg4 + (long)waveBase * 4;
    if (ebw0 < (long)end) {
        DW cur;
        load_dw(beg4 + (long)tid * 4, E, ej, cst, key8, cur);
        for (int c = 0; ; ++c) {
            const long e0 = beg4 + ((long)c * BLOCKT + tid) * 4;
            // (1) masks + issue current chunk's 4 gathers
            bool okv[4];
#pragma unroll
            for (int u = 0; u < 4; ++u) {
                long e = e0 + u;
                okv[u] = (e >= (long)beg) && (e < (long)end);
            }
            float2 gj4[4];
#pragma unroll
            for (int u = 0; u < 4; ++u)
                gj4[u] = okv[u] ? g2[cur.jv[u]] : make_float2(0.f, 0.f);
            // (2) issue next chunk's stream loads (overlap with scan below)
            const bool has_next =
                (beg4 + (((long)c + 1) * BLOCKT + waveBase) * 4) < (long)end;
            DW nxt;
            if (has_next)
                load_dw(beg4 + (((long)c + 1) * BLOCKT + tid) * 4, E, ej, cst, key8, nxt);
            // (3) compute + scan current chunk
            int k[4]; float v[4][1];
#pragma unroll
            for (int u = 0; u < 4; ++u) {
                k[u] = -1; v[u][0] = 0.f;
                if (okv[u]) {
                    __half2 ch = f_as_h2(cur.cv[u]);
                    k[u] = cur.kv[u];                  // direct 7-bit key
                    v[u][0] = gj4[u].x * __low2float(ch) + gj4[u].y * __high2float(ch);
                }
            }
            seg_reduce4<1>(k, v, outl);
            if (!has_next) break;
            cur = nxt;
        }
    }
    __syncthreads();
    if (tid < NPBD && n0 + tid < N)
        out[n0 + tid] = K_OUT * (outp[n0 + tid] + outl[tid]);
}

extern "C" void kernel_launch(void* const* d_in, const int* in_sizes, int n_in,
                              void* d_out, int out_size, void* d_ws, size_t ws_size,
                              hipStream_t stream) {
    const float*  vol  = (const float*)d_in[1];
    const float*  dens = (const float*)d_in[2];
    const float2* dirs = (const float2*)d_in[3];
    const float*  qarr = (const float*)d_in[4];
    const int*    ei   = (const int*)d_in[5];
    const int*    ej   = (const int*)d_in[6];
    const int N = in_sizes[1];
    const int E = in_sizes[4];

    // ws: rowptr int[N+1] | vd f2[N] | g2 f2[N] | outp f[N] | cst h2[E] | key8 u8[E]
    size_t off = 0;
    auto alloc = [&](size_t bytes) { void* r = (char*)d_ws + off;
                                     off = (off + bytes + 15) & ~(size_t)15; return r; };
    int*           rowptr = (int*)          alloc((size_t)(N + 1) * 4);
    float2*        vd     = (float2*)       alloc((size_t)N * 8);
    float2*        g2     = (float2*)       alloc((size_t)N * 8);
    float*         outp   = (float*)        alloc((size_t)N * 4);
    __half2*       cst    = (__half2*)      alloc((size_t)E * 4);
    unsigned char* key8   = (unsigned char*)alloc((size_t)E);
    float*         out    = (float*)d_out;

    const int tb = 256;
    const int gP = (E / 4 + 1 + tb - 1) / tb;   // 4 edges per thread
    const int gB = (N + NPB - 1) / NPB;
    const int gD = (N + NPBD - 1) / NPBD;

    k_prep<<<gP, tb, 0, stream>>>(ei, vol, dens, rowptr, vd, key8, N, E);
    k_AC  <<<gB, BLOCKT, 0, stream>>>(ej, qarr, dirs, vd, rowptr, key8, cst, g2, outp, N, E);
    k_D   <<<gD, BLOCKT, 0, stream>>>(ej, key8, cst, g2, outp, rowptr, out, N, E);
}